// Round 2
// baseline (1869.506 us; speedup 1.0000x reference)
//
#include <hip/hip_runtime.h>

typedef __attribute__((ext_vector_type(8))) __bf16 bf16x8;
typedef __attribute__((ext_vector_type(4))) float f32x4;

#define B_ 16
#define S_ 577
#define D_ 1408
#define H_ 16
#define HD_ 88
#define MROWS (B_*S_)   // 9232
#define N1 (3*D_)       // 4224
#define K_ D_           // 1408

static __device__ __forceinline__ void async16(void* lds, const void* g) {
  __builtin_amdgcn_global_load_lds((const __attribute__((address_space(1))) void*)g,
                                   (__attribute__((address_space(3))) void*)lds, 16, 0, 0);
}

// ---------------- cast fp32 -> bf16 (vectorized) ----------------
__global__ void cast_bf16_kernel(const float* __restrict__ src, __bf16* __restrict__ dst, int n4) {
  int i = blockIdx.x * blockDim.x + threadIdx.x;
  if (i >= n4) return;
  const float4 v = ((const float4*)src)[i];
  __bf16* d = dst + (size_t)i * 4;
  d[0] = (__bf16)v.x; d[1] = (__bf16)v.y; d[2] = (__bf16)v.z; d[3] = (__bf16)v.w;
}

// ---------------- GEMM1: qkv = x @ Wqkv^T + b, fused RoPE+split+permute ----------------
// 128x128 tile, BK=32, 4 waves. Output: bf16 head-major [b*16+h][s][d] into Qb/Kb/Vb.
// N-tiles (128) align with the q/k/v 1408-col sections (1408 = 11*128).
__launch_bounds__(256, 2)
__global__ void gemm_qkv_rope(const __bf16* __restrict__ A, const __bf16* __restrict__ Bm,
                              const float* __restrict__ bias, const float* __restrict__ freqs,
                              __bf16* __restrict__ Qb, __bf16* __restrict__ Kb,
                              __bf16* __restrict__ Vb) {
  __shared__ __bf16 As[128 * 32];
  __shared__ __bf16 Bs[128 * 32];
  const int tid = threadIdx.x;
  const int w = tid >> 6, l = tid & 63;
  const int m0 = blockIdx.y * 128, n0 = blockIdx.x * 128;
  const int wr = w & 1, wc = w >> 1;
  const int M = MROWS, N = N1, K = K_;

  f32x4 acc[4][4];
#pragma unroll
  for (int m = 0; m < 4; ++m)
#pragma unroll
    for (int n = 0; n < 4; ++n) acc[m][n] = (f32x4){0.f, 0.f, 0.f, 0.f};

  int arow0 = m0 + w * 32 + (l >> 2);      if (arow0 >= M) arow0 = M - 1;
  int arow1 = m0 + w * 32 + 16 + (l >> 2); if (arow1 >= M) arow1 = M - 1;
  const __bf16* ag0 = A + (size_t)arow0 * K + (l & 3) * 8;
  const __bf16* ag1 = A + (size_t)arow1 * K + (l & 3) * 8;
  const __bf16* bg0 = Bm + (size_t)(n0 + w * 32 + (l >> 2)) * K + (l & 3) * 8;
  const __bf16* bg1 = Bm + (size_t)(n0 + w * 32 + 16 + (l >> 2)) * K + (l & 3) * 8;
  __bf16* asl0 = &As[(w * 32) * 32];
  __bf16* asl1 = &As[(w * 32 + 16) * 32];
  __bf16* bsl0 = &Bs[(w * 32) * 32];
  __bf16* bsl1 = &Bs[(w * 32 + 16) * 32];

  for (int k0 = 0; k0 < K; k0 += 32) {
    async16(asl0, ag0 + k0);
    async16(asl1, ag1 + k0);
    async16(bsl0, bg0 + k0);
    async16(bsl1, bg1 + k0);
    __syncthreads();
    bf16x8 a[4], b[4];
#pragma unroll
    for (int m = 0; m < 4; ++m)
      a[m] = *(const bf16x8*)&As[(wr * 64 + m * 16 + (l & 15)) * 32 + (l >> 4) * 8];
#pragma unroll
    for (int n = 0; n < 4; ++n)
      b[n] = *(const bf16x8*)&Bs[(wc * 64 + n * 16 + (l & 15)) * 32 + (l >> 4) * 8];
#pragma unroll
    for (int m = 0; m < 4; ++m)
#pragma unroll
      for (int n = 0; n < 4; ++n)
        acc[m][n] = __builtin_amdgcn_mfma_f32_16x16x32_bf16(a[m], b[n], acc[m][n], 0, 0, 0);
    __syncthreads();
  }

  // ---- fused epilogue: bias + RoPE (q,k) + head-major bf16 store ----
  const int sect = n0 / 1408;  // 0=q 1=k 2=v, uniform per block
  __bf16* dst = (sect == 0) ? Qb : (sect == 1 ? Kb : Vb);
#pragma unroll
  for (int n = 0; n < 4; ++n) {
    const int col = n0 + wc * 64 + n * 16 + (l & 15);
    const int cin = col - sect * 1408;
    const int h = cin / 88, d = cin % 88;
    const float bv = bias[col];
    const int i2 = d & ~1;                    // rope pair base
    const float sgn = (d & 1) ? 1.f : -1.f;   // even: re = e*c - o*s ; odd: ro = e*s + o*c
#pragma unroll
    for (int m = 0; m < 4; ++m) {
      const int rbase = m0 + wr * 64 + m * 16 + (l >> 4) * 4;
#pragma unroll
      for (int j = 0; j < 4; ++j) {
        const int r = rbase + j;
        float val = acc[m][n][j] + bv;
        const int s = r % 577;                // safe even for clamped OOB rows
        float out;
        if (sect < 2) {
          const float2 cs = *(const float2*)&freqs[s * 88 + i2];
          const float p = __shfl_xor(val, 1); // partner (d^1), same row
          out = val * cs.x + sgn * p * cs.y;
        } else {
          out = val;
        }
        if (r < M) {
          const int b = r / 577;
          dst[((size_t)(b * 16 + h) * 577 + s) * 88 + d] = (__bf16)out;
        }
      }
    }
  }
}

// ---------------- GEMM2: out = ctx @ Wo^T + bo (fp32 out) ----------------
__launch_bounds__(256, 2)
__global__ void gemm_out_bias(const __bf16* __restrict__ A, const __bf16* __restrict__ Bm,
                              const float* __restrict__ bias, float* __restrict__ C,
                              int M, int N, int K) {
  __shared__ __bf16 As[128 * 32];
  __shared__ __bf16 Bs[128 * 32];
  const int tid = threadIdx.x;
  const int w = tid >> 6, l = tid & 63;
  const int m0 = blockIdx.y * 128, n0 = blockIdx.x * 128;
  const int wr = w & 1, wc = w >> 1;

  f32x4 acc[4][4];
#pragma unroll
  for (int m = 0; m < 4; ++m)
#pragma unroll
    for (int n = 0; n < 4; ++n) acc[m][n] = (f32x4){0.f, 0.f, 0.f, 0.f};

  int arow0 = m0 + w * 32 + (l >> 2);      if (arow0 >= M) arow0 = M - 1;
  int arow1 = m0 + w * 32 + 16 + (l >> 2); if (arow1 >= M) arow1 = M - 1;
  const __bf16* ag0 = A + (size_t)arow0 * K + (l & 3) * 8;
  const __bf16* ag1 = A + (size_t)arow1 * K + (l & 3) * 8;
  const __bf16* bg0 = Bm + (size_t)(n0 + w * 32 + (l >> 2)) * K + (l & 3) * 8;
  const __bf16* bg1 = Bm + (size_t)(n0 + w * 32 + 16 + (l >> 2)) * K + (l & 3) * 8;
  __bf16* asl0 = &As[(w * 32) * 32];
  __bf16* asl1 = &As[(w * 32 + 16) * 32];
  __bf16* bsl0 = &Bs[(w * 32) * 32];
  __bf16* bsl1 = &Bs[(w * 32 + 16) * 32];

  for (int k0 = 0; k0 < K; k0 += 32) {
    async16(asl0, ag0 + k0);
    async16(asl1, ag1 + k0);
    async16(bsl0, bg0 + k0);
    async16(bsl1, bg1 + k0);
    __syncthreads();
    bf16x8 a[4], b[4];
#pragma unroll
    for (int m = 0; m < 4; ++m)
      a[m] = *(const bf16x8*)&As[(wr * 64 + m * 16 + (l & 15)) * 32 + (l >> 4) * 8];
#pragma unroll
    for (int n = 0; n < 4; ++n)
      b[n] = *(const bf16x8*)&Bs[(wc * 64 + n * 16 + (l & 15)) * 32 + (l >> 4) * 8];
#pragma unroll
    for (int m = 0; m < 4; ++m)
#pragma unroll
      for (int n = 0; n < 4; ++n)
        acc[m][n] = __builtin_amdgcn_mfma_f32_16x16x32_bf16(a[m], b[n], acc[m][n], 0, 0, 0);
    __syncthreads();
  }

#pragma unroll
  for (int n = 0; n < 4; ++n) {
    int col = n0 + wc * 64 + n * 16 + (l & 15);
    float bv = bias[col];
#pragma unroll
    for (int m = 0; m < 4; ++m) {
      int rbase = m0 + wr * 64 + m * 16 + (l >> 4) * 4;
#pragma unroll
      for (int j = 0; j < 4; ++j) {
        int r = rbase + j;
        if (r < M) C[(size_t)r * N + col] = acc[m][n][j] + bv;
      }
    }
  }
}

// ---------------- attention: per (b*h, 32-row q-tile) ----------------
#define SCALE 0.10660035817780521f

__launch_bounds__(256, 1)
__global__ void attn_kernel(const __bf16* __restrict__ Q, const __bf16* __restrict__ Kt,
                            const __bf16* __restrict__ V, __bf16* __restrict__ ctx) {
  __shared__ __align__(16) __bf16 Qs[32 * 104];   // stride 104: 2-way banks
  __shared__ __align__(16) __bf16 Ks[32 * 104];
  __shared__ __align__(16) __bf16 Vt[96 * 72];    // V^T chunk [d][s_local]
  __shared__ __align__(16) float  Ssc[32 * 652];  // fp32 scores -> exp() in place
  __shared__ float  invL[32];

  const int tid = threadIdx.x;
  const int w = tid >> 6, l = tid & 63;
  const int bh = blockIdx.x;        // b*16+h
  const int q0 = blockIdx.y * 32;
  const __bf16* qp = Q + (size_t)bh * 577 * 88;
  const __bf16* kp = Kt + (size_t)bh * 577 * 88;
  const __bf16* vp = V + (size_t)bh * 577 * 88;

  // zero Vt pad rows (d=88..95) once; staging never touches them
  for (int i = tid; i < 8 * 72; i += 256) Vt[(88 + i / 72) * 72 + i % 72] = (__bf16)0.f;

  // stage Q tile [32][104], zero-padded
  for (int i = tid; i < 32 * 52; i += 256) {
    int r = i / 52, c = i % 52;
    unsigned int val = 0;
    int gr = q0 + r;
    if (c < 44 && gr < 577) val = *(const unsigned int*)(qp + (size_t)gr * 88 + c * 2);
    *(unsigned int*)&Qs[r * 104 + c * 2] = val;
  }

  const int fr = w & 1;        // row-frag for this wave
  const int fcq = w >> 1;      // col-frag (QK^T)
  // ---- Phase A: scores = scale * Q K^T into Ssc ----
  for (int ck = 0; ck < 19; ++ck) {
    __syncthreads();  // previous-iteration readers done before Ks overwrite
    for (int i = tid; i < 32 * 52; i += 256) {
      int r = i / 52, c = i % 52;
      unsigned int val = 0;
      int gr = ck * 32 + r;
      if (c < 44 && gr < 577) val = *(const unsigned int*)(kp + (size_t)gr * 88 + c * 2);
      *(unsigned int*)&Ks[r * 104 + c * 2] = val;
    }
    __syncthreads();
    f32x4 acc = (f32x4){0.f, 0.f, 0.f, 0.f};
#pragma unroll
    for (int kk = 0; kk < 3; ++kk) {
      bf16x8 a  = *(const bf16x8*)&Qs[(fr * 16 + (l & 15)) * 104 + kk * 32 + (l >> 4) * 8];
      bf16x8 bb = *(const bf16x8*)&Ks[(fcq * 16 + (l & 15)) * 104 + kk * 32 + (l >> 4) * 8];
      acc = __builtin_amdgcn_mfma_f32_16x16x32_bf16(a, bb, acc, 0, 0, 0);
    }
#pragma unroll
    for (int j = 0; j < 4; ++j)
      Ssc[(fr * 16 + (l >> 4) * 4 + j) * 652 + ck * 32 + fcq * 16 + (l & 15)] = acc[j] * SCALE;
  }
  __syncthreads();

  // ---- Phase B: softmax (8 threads per row), exp() written back in place ----
  {
    int row = tid >> 3, g = tid & 7;
    float m = -1e30f;
    for (int c = g; c < 577; c += 8) m = fmaxf(m, Ssc[row * 652 + c]);
#pragma unroll
    for (int o = 1; o < 8; o <<= 1) m = fmaxf(m, __shfl_xor(m, o));
    float sum = 0.f;
    for (int c = g; c < 640; c += 8) {
      float p = 0.f;
      if (c < 577) { p = __expf(Ssc[row * 652 + c] - m); sum += p; }
      Ssc[row * 652 + c] = p;   // also zeroes pad cols 577..639
    }
#pragma unroll
    for (int o = 1; o < 8; o <<= 1) sum += __shfl_xor(sum, o);
    if (g == 0) invL[row] = 1.f / sum;
  }

  // ---- Phase C: ctx = P V  (A-frag built from fp32 Ssc on the fly) ----
  f32x4 pv[3];
#pragma unroll
  for (int c = 0; c < 3; ++c) pv[c] = (f32x4){0.f, 0.f, 0.f, 0.f};
  const int fcb = (w >> 1) * 3;
  for (int vo = 0; vo < 10; ++vo) {
    __syncthreads();  // softmax done (first iter) / prior Vt readers done
    for (int i = tid; i < 64 * 88; i += 256) {
      int sl = i / 88, d2 = i % 88;
      int gs = vo * 64 + sl; if (gs > 576) gs = 576;  // clamped dup rows * P=0
      Vt[d2 * 72 + sl] = vp[(size_t)gs * 88 + d2];
    }
    __syncthreads();
#pragma unroll
    for (int vv = 0; vv < 2; ++vv) {
      int vk = vo * 2 + vv;
      const float* sp = &Ssc[(fr * 16 + (l & 15)) * 652 + vk * 32 + (l >> 4) * 8];
      f32x4 p0 = *(const f32x4*)sp;
      f32x4 p1 = *(const f32x4*)(sp + 4);
      bf16x8 a;
      a[0] = (__bf16)p0[0]; a[1] = (__bf16)p0[1]; a[2] = (__bf16)p0[2]; a[3] = (__bf16)p0[3];
      a[4] = (__bf16)p1[0]; a[5] = (__bf16)p1[1]; a[6] = (__bf16)p1[2]; a[7] = (__bf16)p1[3];
#pragma unroll
      for (int c = 0; c < 3; ++c) {
        bf16x8 bv = *(const bf16x8*)&Vt[((fcb + c) * 16 + (l & 15)) * 72 + vv * 32 + (l >> 4) * 8];
        pv[c] = __builtin_amdgcn_mfma_f32_16x16x32_bf16(a, bv, pv[c], 0, 0, 0);
      }
    }
  }

  // ---- epilogue: ctx[b*577+s][h*88+d] bf16 ----
  {
    int b = bh >> 4, h = bh & 15;
#pragma unroll
    for (int c = 0; c < 3; ++c) {
      int col = (fcb + c) * 16 + (l & 15);
      if (col >= 88) continue;
#pragma unroll
      for (int j = 0; j < 4; ++j) {
        int r = fr * 16 + (l >> 4) * 4 + j;
        int gs = q0 + r;
        if (gs < 577) {
          float val = pv[c][j] * invL[r];
          ctx[((size_t)(b * 577 + gs)) * 1408 + h * 88 + col] = (__bf16)val;
        }
      }
    }
  }
}

extern "C" void kernel_launch(void* const* d_in, const int* in_sizes, int n_in,
                              void* d_out, int out_size, void* d_ws, size_t ws_size,
                              hipStream_t stream) {
  const float* hs    = (const float*)d_in[0];
  const float* freqs = (const float*)d_in[1];
  const float* wqkv  = (const float*)d_in[2];
  const float* bqkv  = (const float*)d_in[3];
  const float* wo    = (const float*)d_in[4];
  const float* bo    = (const float*)d_in[5];
  float* out = (float*)d_out;

  char* ws = (char*)d_ws;
  size_t off = 0;
  auto alloc = [&](size_t bytes) {
    void* p = ws + off;
    off += (bytes + 255) & ~(size_t)255;
    return p;
  };
  // x_bf dead after GEMM1 -> ctx_bf aliases it. Peak ws = ~120 MB.
  __bf16* x_bf    = (__bf16*)alloc((size_t)MROWS * K_ * 2);
  __bf16* ctx_bf  = x_bf;
  __bf16* wqkv_bf = (__bf16*)alloc((size_t)N1 * K_ * 2);
  __bf16* wo_bf   = (__bf16*)alloc((size_t)D_ * K_ * 2);
  __bf16* q_bf    = (__bf16*)alloc((size_t)MROWS * D_ * 2);
  __bf16* k_bf    = (__bf16*)alloc((size_t)MROWS * D_ * 2);
  __bf16* v_bf    = (__bf16*)alloc((size_t)MROWS * D_ * 2);

  // casts
  cast_bf16_kernel<<<(MROWS * K_ / 4 + 255) / 256, 256, 0, stream>>>(hs, x_bf, MROWS * K_ / 4);
  cast_bf16_kernel<<<(N1 * K_ / 4 + 255) / 256, 256, 0, stream>>>(wqkv, wqkv_bf, N1 * K_ / 4);
  cast_bf16_kernel<<<(D_ * K_ / 4 + 255) / 256, 256, 0, stream>>>(wo, wo_bf, D_ * K_ / 4);
  // QKV projection + bias + RoPE + split + head-major permute (bf16 out)
  gemm_qkv_rope<<<dim3(N1 / 128, (MROWS + 127) / 128), 256, 0, stream>>>(
      x_bf, wqkv_bf, bqkv, freqs, q_bf, k_bf, v_bf);
  // attention
  attn_kernel<<<dim3(256, 19), 256, 0, stream>>>(q_bf, k_bf, v_bf, ctx_bf);
  // output projection -> d_out (fp32)
  gemm_out_bias<<<dim3(D_ / 128, (MROWS + 127) / 128), 256, 0, stream>>>(
      ctx_bf, wo_bf, bo, out, MROWS, D_, K_);
}

// Round 3
// 444.806 us; speedup vs baseline: 4.2030x; 4.2030x over previous
//
#include <hip/hip_runtime.h>

typedef __attribute__((ext_vector_type(8))) __bf16 bf16x8;
typedef __attribute__((ext_vector_type(4))) float f32x4;
typedef __attribute__((ext_vector_type(4))) unsigned int uint4v;

#define B_ 16
#define S_ 577
#define D_ 1408
#define H_ 16
#define HD_ 88
#define MROWS (B_*S_)   // 9232
#define N1 (3*D_)       // 4224
#define K_ D_           // 1408
#define VT_LD 592       // V^T scratch leading dim (multiple of 8 so rows are 16B-aligned)
#define SCALE 0.10660035817780521f

static __device__ __forceinline__ void async16(void* lds, const void* g) {
  __builtin_amdgcn_global_load_lds((const __attribute__((address_space(1))) void*)g,
                                   (__attribute__((address_space(3))) void*)lds, 16, 0, 0);
}

// ---------------- cast fp32 -> bf16 (vectorized) ----------------
__global__ void cast_bf16_kernel(const float* __restrict__ src, __bf16* __restrict__ dst, int n4) {
  int i = blockIdx.x * blockDim.x + threadIdx.x;
  if (i >= n4) return;
  const float4 v = ((const float4*)src)[i];
  __bf16* d = dst + (size_t)i * 4;
  d[0] = (__bf16)v.x; d[1] = (__bf16)v.y; d[2] = (__bf16)v.z; d[3] = (__bf16)v.w;
}

// ---------------- GEMM1: qkv = x @ Wqkv^T + b, fused RoPE+split+permute ----------------
__launch_bounds__(256, 2)
__global__ void gemm_qkv_rope(const __bf16* __restrict__ A, const __bf16* __restrict__ Bm,
                              const float* __restrict__ bias, const float* __restrict__ freqs,
                              __bf16* __restrict__ Qb, __bf16* __restrict__ Kb,
                              __bf16* __restrict__ Vb) {
  __shared__ __bf16 As[128 * 32];
  __shared__ __bf16 Bs[128 * 32];
  const int tid = threadIdx.x;
  const int w = tid >> 6, l = tid & 63;
  const int m0 = blockIdx.y * 128, n0 = blockIdx.x * 128;
  const int wr = w & 1, wc = w >> 1;
  const int M = MROWS, K = K_;

  f32x4 acc[4][4];
#pragma unroll
  for (int m = 0; m < 4; ++m)
#pragma unroll
    for (int n = 0; n < 4; ++n) acc[m][n] = (f32x4){0.f, 0.f, 0.f, 0.f};

  int arow0 = m0 + w * 32 + (l >> 2);      if (arow0 >= M) arow0 = M - 1;
  int arow1 = m0 + w * 32 + 16 + (l >> 2); if (arow1 >= M) arow1 = M - 1;
  const __bf16* ag0 = A + (size_t)arow0 * K + (l & 3) * 8;
  const __bf16* ag1 = A + (size_t)arow1 * K + (l & 3) * 8;
  const __bf16* bg0 = Bm + (size_t)(n0 + w * 32 + (l >> 2)) * K + (l & 3) * 8;
  const __bf16* bg1 = Bm + (size_t)(n0 + w * 32 + 16 + (l >> 2)) * K + (l & 3) * 8;
  __bf16* asl0 = &As[(w * 32) * 32];
  __bf16* asl1 = &As[(w * 32 + 16) * 32];
  __bf16* bsl0 = &Bs[(w * 32) * 32];
  __bf16* bsl1 = &Bs[(w * 32 + 16) * 32];

  for (int k0 = 0; k0 < K; k0 += 32) {
    async16(asl0, ag0 + k0);
    async16(asl1, ag1 + k0);
    async16(bsl0, bg0 + k0);
    async16(bsl1, bg1 + k0);
    __syncthreads();
    bf16x8 a[4], b[4];
#pragma unroll
    for (int m = 0; m < 4; ++m)
      a[m] = *(const bf16x8*)&As[(wr * 64 + m * 16 + (l & 15)) * 32 + (l >> 4) * 8];
#pragma unroll
    for (int n = 0; n < 4; ++n)
      b[n] = *(const bf16x8*)&Bs[(wc * 64 + n * 16 + (l & 15)) * 32 + (l >> 4) * 8];
#pragma unroll
    for (int m = 0; m < 4; ++m)
#pragma unroll
      for (int n = 0; n < 4; ++n)
        acc[m][n] = __builtin_amdgcn_mfma_f32_16x16x32_bf16(a[m], b[n], acc[m][n], 0, 0, 0);
    __syncthreads();
  }

  const int sect = n0 / 1408;  // 0=q 1=k 2=v, uniform per block
  __bf16* dst = (sect == 0) ? Qb : (sect == 1 ? Kb : Vb);
#pragma unroll
  for (int n = 0; n < 4; ++n) {
    const int col = n0 + wc * 64 + n * 16 + (l & 15);
    const int cin = col - sect * 1408;
    const int h = cin / 88, d = cin % 88;
    const float bv = bias[col];
    const int i2 = d & ~1;
    const float sgn = (d & 1) ? 1.f : -1.f;
#pragma unroll
    for (int m = 0; m < 4; ++m) {
      const int rbase = m0 + wr * 64 + m * 16 + (l >> 4) * 4;
#pragma unroll
      for (int j = 0; j < 4; ++j) {
        const int r = rbase + j;
        float val = acc[m][n][j] + bv;
        const int s = r % 577;
        float outv;
        if (sect < 2) {
          const float2 cs = *(const float2*)&freqs[s * 88 + i2];
          const float p = __shfl_xor(val, 1);
          outv = val * cs.x + sgn * p * cs.y;
        } else {
          outv = val;
        }
        if (r < M) {
          const int b = r / 577;
          dst[((size_t)(b * 16 + h) * 577 + s) * 88 + d] = (__bf16)outv;
        }
      }
    }
  }
}

// ---------------- GEMM2: out = ctx @ Wo^T + bo (fp32 out) ----------------
__launch_bounds__(256, 2)
__global__ void gemm_out_bias(const __bf16* __restrict__ A, const __bf16* __restrict__ Bm,
                              const float* __restrict__ bias, float* __restrict__ C,
                              int M, int N, int K) {
  __shared__ __bf16 As[128 * 32];
  __shared__ __bf16 Bs[128 * 32];
  const int tid = threadIdx.x;
  const int w = tid >> 6, l = tid & 63;
  const int m0 = blockIdx.y * 128, n0 = blockIdx.x * 128;
  const int wr = w & 1, wc = w >> 1;

  f32x4 acc[4][4];
#pragma unroll
  for (int m = 0; m < 4; ++m)
#pragma unroll
    for (int n = 0; n < 4; ++n) acc[m][n] = (f32x4){0.f, 0.f, 0.f, 0.f};

  int arow0 = m0 + w * 32 + (l >> 2);      if (arow0 >= M) arow0 = M - 1;
  int arow1 = m0 + w * 32 + 16 + (l >> 2); if (arow1 >= M) arow1 = M - 1;
  const __bf16* ag0 = A + (size_t)arow0 * K + (l & 3) * 8;
  const __bf16* ag1 = A + (size_t)arow1 * K + (l & 3) * 8;
  const __bf16* bg0 = Bm + (size_t)(n0 + w * 32 + (l >> 2)) * K + (l & 3) * 8;
  const __bf16* bg1 = Bm + (size_t)(n0 + w * 32 + 16 + (l >> 2)) * K + (l & 3) * 8;
  __bf16* asl0 = &As[(w * 32) * 32];
  __bf16* asl1 = &As[(w * 32 + 16) * 32];
  __bf16* bsl0 = &Bs[(w * 32) * 32];
  __bf16* bsl1 = &Bs[(w * 32 + 16) * 32];

  for (int k0 = 0; k0 < K; k0 += 32) {
    async16(asl0, ag0 + k0);
    async16(asl1, ag1 + k0);
    async16(bsl0, bg0 + k0);
    async16(bsl1, bg1 + k0);
    __syncthreads();
    bf16x8 a[4], b[4];
#pragma unroll
    for (int m = 0; m < 4; ++m)
      a[m] = *(const bf16x8*)&As[(wr * 64 + m * 16 + (l & 15)) * 32 + (l >> 4) * 8];
#pragma unroll
    for (int n = 0; n < 4; ++n)
      b[n] = *(const bf16x8*)&Bs[(wc * 64 + n * 16 + (l & 15)) * 32 + (l >> 4) * 8];
#pragma unroll
    for (int m = 0; m < 4; ++m)
#pragma unroll
      for (int n = 0; n < 4; ++n)
        acc[m][n] = __builtin_amdgcn_mfma_f32_16x16x32_bf16(a[m], b[n], acc[m][n], 0, 0, 0);
    __syncthreads();
  }

#pragma unroll
  for (int n = 0; n < 4; ++n) {
    int col = n0 + wc * 64 + n * 16 + (l & 15);
    float bv = bias[col];
#pragma unroll
    for (int m = 0; m < 4; ++m) {
      int rbase = m0 + wr * 64 + m * 16 + (l >> 4) * 4;
#pragma unroll
      for (int j = 0; j < 4; ++j) {
        int r = rbase + j;
        if (r < M) C[(size_t)r * N + col] = acc[m][n][j] + bv;
      }
    }
  }
}

// ---------------- V transpose: v_bf [bh][577][88] -> Vt_g [bh][88][592] ----------------
__global__ void transpose_v(const __bf16* __restrict__ V, __bf16* __restrict__ Vt_g) {
  __shared__ __bf16 Ls[64 * 104];
  const int bh = blockIdx.x, t = blockIdx.y, s0 = t * 64;
  const int tid = threadIdx.x;
  const __bf16* vp = V + (size_t)bh * 577 * 88;
  for (int i = tid; i < 64 * 11; i += 256) {
    int r = i / 11, off = i % 11;
    int gs = s0 + r; if (gs > 576) gs = 576;
    *(uint4v*)&Ls[r * 104 + off * 8] = *(const uint4v*)(vp + (size_t)gs * 88 + off * 8);
  }
  __syncthreads();
  for (int i = tid; i < 88 * 8; i += 256) {
    int d = i / 8, so = (i % 8) * 8;
    int sc_ = s0 + so;
    if (sc_ < VT_LD) {
      __bf16 tmp[8];
#pragma unroll
      for (int j = 0; j < 8; ++j) tmp[j] = Ls[(so + j) * 104 + d];
      *(uint4v*)&Vt_g[((size_t)bh * 88 + d) * VT_LD + sc_] = *(uint4v*)tmp;
    }
  }
}

// ---------------- flash attention: block = (bh, 128 q-rows), 4 waves x 32 rows ----------------
// LDS (elems of bf16): [0,12288) Qs[128][96] (reused as P: 4 x [32][72]);
//                      [12288,17920) Ks[64][88] linear; [17920,26368) Vt[96][88] linear.
__launch_bounds__(256, 3)
__global__ void attn_kernel(const __bf16* __restrict__ Q, const __bf16* __restrict__ K,
                            const __bf16* __restrict__ Vt_gp, __bf16* __restrict__ ctx) {
  __shared__ __bf16 lds[26368];
  const int tid = threadIdx.x;
  const int w = tid >> 6, l = tid & 63;
  const int bh = blockIdx.x;
  const int q0 = blockIdx.y * 128;
  const __bf16* qp = Q + (size_t)bh * 577 * 88;
  const __bf16* kp = K + (size_t)bh * 577 * 88;
  const __bf16* vtp = Vt_gp + (size_t)bh * 88 * VT_LD;
  __bf16* Qs = lds;             // [128][96]
  __bf16* Ks = lds + 12288;     // [64][88]
  __bf16* Vt = lds + 17920;     // [96][88] (rows 0..87 staged; 88+ junk, unstored cols only)
  __bf16* Pw = lds + w * 2304;  // per-wave P [32][72]

  // stage Q [128][96], zero pad cols 88..95 (zeros null the k-spill in QK^T)
  for (int i = tid; i < 128 * 11; i += 256) {
    int r = i / 11, off = i % 11;
    int gr = q0 + r; if (gr > 576) gr = 576;
    *(uint4v*)&Qs[r * 96 + off * 8] = *(const uint4v*)(qp + (size_t)gr * 88 + off * 8);
  }
  if (tid < 128) { uint4v z = 0; *(uint4v*)&Qs[tid * 96 + 88] = z; }
  __syncthreads();

  bf16x8 qf[2][3];
#pragma unroll
  for (int mg = 0; mg < 2; ++mg)
#pragma unroll
    for (int kk = 0; kk < 3; ++kk)
      qf[mg][kk] = *(const bf16x8*)&Qs[(w * 32 + mg * 16 + (l & 15)) * 96 + kk * 32 + (l >> 4) * 8];

  // per-lane global offsets for this wave's staging chunks (c = w + 4k, 27 total: 11 K + 16 V)
  int preA[7], preB[7];
#pragma unroll
  for (int kch = 0; kch < 7; ++kch) {
    int c = w + 4 * kch;
    int a = 0, b2 = 0;
    if (c < 11) a = c * 512 + l * 8;
    else if (c < 27) { int e = (c - 11) * 512 + l * 8; a = (e / 88) * VT_LD; b2 = e % 88; }
    preA[kch] = a; preB[kch] = b2;
  }

  f32x4 oacc[2][6];
#pragma unroll
  for (int mg = 0; mg < 2; ++mg)
#pragma unroll
    for (int dn = 0; dn < 6; ++dn) oacc[mg][dn] = (f32x4){0.f, 0.f, 0.f, 0.f};
  f32x4 mrun[2], lrun[2];
  mrun[0] = -1e30f; mrun[1] = -1e30f;
  lrun[0] = 0.f; lrun[1] = 0.f;

  for (int t = 0; t < 10; ++t) {
    const int s0 = t * 64;
    if (t) __syncthreads();  // prior tile's K/V readers done
#pragma unroll
    for (int kch = 0; kch < 7; ++kch) {
      int c = w + 4 * kch;
      if (c < 11) {
        async16(Ks + c * 512, kp + (size_t)s0 * 88 + preA[kch]);
      } else if (c < 27) {
        int g = s0 + preB[kch]; if (g > 584) g = 584;  // clamp: stay in-row, 16B-aligned
        async16(Vt + (c - 11) * 512, vtp + preA[kch] + g);
      }
    }
    __syncthreads();  // staging drained (compiler emits vmcnt(0) before barrier)

    // ---- QK^T ----
    f32x4 sc[2][4];
#pragma unroll
    for (int mg = 0; mg < 2; ++mg)
#pragma unroll
      for (int n = 0; n < 4; ++n) sc[mg][n] = (f32x4){0.f, 0.f, 0.f, 0.f};
#pragma unroll
    for (int n = 0; n < 4; ++n) {
#pragma unroll
      for (int kk = 0; kk < 3; ++kk) {
        bf16x8 kf = *(const bf16x8*)&Ks[(n * 16 + (l & 15)) * 88 + kk * 32 + (l >> 4) * 8];
        sc[0][n] = __builtin_amdgcn_mfma_f32_16x16x32_bf16(qf[0][kk], kf, sc[0][n], 0, 0, 0);
        sc[1][n] = __builtin_amdgcn_mfma_f32_16x16x32_bf16(qf[1][kk], kf, sc[1][n], 0, 0, 0);
      }
    }

    // ---- online softmax ----
    f32x4 tmax[2];
    tmax[0] = -1e30f; tmax[1] = -1e30f;
#pragma unroll
    for (int n = 0; n < 4; ++n) {
      const int kc = s0 + n * 16 + (l & 15);
      const bool valid = kc < 577;
#pragma unroll
      for (int mg = 0; mg < 2; ++mg)
#pragma unroll
        for (int j = 0; j < 4; ++j) {
          float v = valid ? sc[mg][n][j] * SCALE : -1e30f;
          sc[mg][n][j] = v;
          tmax[mg][j] = fmaxf(tmax[mg][j], v);
        }
    }
#pragma unroll
    for (int o = 1; o < 16; o <<= 1)
#pragma unroll
      for (int mg = 0; mg < 2; ++mg)
#pragma unroll
        for (int j = 0; j < 4; ++j)
          tmax[mg][j] = fmaxf(tmax[mg][j], __shfl_xor(tmax[mg][j], o));
#pragma unroll
    for (int mg = 0; mg < 2; ++mg)
#pragma unroll
      for (int j = 0; j < 4; ++j) {
        float mo = mrun[mg][j];
        float mn = fmaxf(mo, tmax[mg][j]);
        float sf = __expf(mo - mn);
        mrun[mg][j] = mn;
        lrun[mg][j] *= sf;
#pragma unroll
        for (int dn = 0; dn < 6; ++dn) oacc[mg][dn][j] *= sf;
      }
#pragma unroll
    for (int mg = 0; mg < 2; ++mg)
#pragma unroll
      for (int n = 0; n < 4; ++n)
#pragma unroll
        for (int j = 0; j < 4; ++j) {
          float p = __expf(sc[mg][n][j] - mrun[mg][j]);
          lrun[mg][j] += p;
          Pw[(mg * 16 + (l >> 4) * 4 + j) * 72 + n * 16 + (l & 15)] = (__bf16)p;
        }

    // ---- PV (P round-trip is wave-private: no barrier needed) ----
#pragma unroll
    for (int ks = 0; ks < 2; ++ks) {
      bf16x8 pa0 = *(const bf16x8*)&Pw[((l & 15)) * 72 + ks * 32 + (l >> 4) * 8];
      bf16x8 pa1 = *(const bf16x8*)&Pw[(16 + (l & 15)) * 72 + ks * 32 + (l >> 4) * 8];
#pragma unroll
      for (int dn = 0; dn < 6; ++dn) {
        bf16x8 vb = *(const bf16x8*)&Vt[(dn * 16 + (l & 15)) * 88 + ks * 32 + (l >> 4) * 8];
        oacc[0][dn] = __builtin_amdgcn_mfma_f32_16x16x32_bf16(pa0, vb, oacc[0][dn], 0, 0, 0);
        oacc[1][dn] = __builtin_amdgcn_mfma_f32_16x16x32_bf16(pa1, vb, oacc[1][dn], 0, 0, 0);
      }
    }
  }

  // reduce l across the 16-lane k-groups, then normalize + store
#pragma unroll
  for (int o = 1; o < 16; o <<= 1)
#pragma unroll
    for (int mg = 0; mg < 2; ++mg)
#pragma unroll
      for (int j = 0; j < 4; ++j)
        lrun[mg][j] += __shfl_xor(lrun[mg][j], o);

  const int b = bh >> 4, h = bh & 15;
#pragma unroll
  for (int mg = 0; mg < 2; ++mg) {
    float inv[4];
#pragma unroll
    for (int j = 0; j < 4; ++j) inv[j] = 1.f / lrun[mg][j];
    const int sqb = q0 + w * 32 + mg * 16 + (l >> 4) * 4;
#pragma unroll
    for (int dn = 0; dn < 6; ++dn) {
      const int d = dn * 16 + (l & 15);
      if (d >= 88) continue;
#pragma unroll
      for (int j = 0; j < 4; ++j) {
        const int sq = sqb + j;
        if (sq < 577)
          ctx[((size_t)(b * 577 + sq)) * 1408 + h * 88 + d] = (__bf16)(oacc[mg][dn][j] * inv[j]);
      }
    }
  }
}

extern "C" void kernel_launch(void* const* d_in, const int* in_sizes, int n_in,
                              void* d_out, int out_size, void* d_ws, size_t ws_size,
                              hipStream_t stream) {
  const float* hs    = (const float*)d_in[0];
  const float* freqs = (const float*)d_in[1];
  const float* wqkv  = (const float*)d_in[2];
  const float* bqkv  = (const float*)d_in[3];
  const float* wo    = (const float*)d_in[4];
  const float* bo    = (const float*)d_in[5];
  float* out = (float*)d_out;

  char* ws = (char*)d_ws;
  size_t off = 0;
  auto alloc = [&](size_t bytes) {
    void* p = ws + off;
    off += (bytes + 255) & ~(size_t)255;
    return p;
  };
  __bf16* x_bf    = (__bf16*)alloc((size_t)MROWS * K_ * 2);
  __bf16* ctx_bf  = x_bf;  // aliased: x dead after GEMM1
  __bf16* wqkv_bf = (__bf16*)alloc((size_t)N1 * K_ * 2);
  __bf16* wo_bf   = (__bf16*)alloc((size_t)D_ * K_ * 2);
  __bf16* q_bf    = (__bf16*)alloc((size_t)MROWS * D_ * 2);
  __bf16* k_bf    = (__bf16*)alloc((size_t)MROWS * D_ * 2);
  __bf16* v_bf    = (__bf16*)alloc((size_t)MROWS * D_ * 2);
  // V^T scratch lives in d_out (26.7 MB < 52 MB); GEMM2 overwrites d_out afterwards.
  __bf16* vt_g    = (__bf16*)d_out;

  cast_bf16_kernel<<<(MROWS * K_ / 4 + 255) / 256, 256, 0, stream>>>(hs, x_bf, MROWS * K_ / 4);
  cast_bf16_kernel<<<(N1 * K_ / 4 + 255) / 256, 256, 0, stream>>>(wqkv, wqkv_bf, N1 * K_ / 4);
  cast_bf16_kernel<<<(D_ * K_ / 4 + 255) / 256, 256, 0, stream>>>(wo, wo_bf, D_ * K_ / 4);

  gemm_qkv_rope<<<dim3(N1 / 128, (MROWS + 127) / 128), 256, 0, stream>>>(
      x_bf, wqkv_bf, bqkv, freqs, q_bf, k_bf, v_bf);

  transpose_v<<<dim3(256, 10), 256, 0, stream>>>(v_bf, vt_g);

  attn_kernel<<<dim3(256, 5), 256, 0, stream>>>(q_bf, k_bf, vt_g, ctx_bf);

  gemm_out_bias<<<dim3(D_ / 128, (MROWS + 127) / 128), 256, 0, stream>>>(
      ctx_bf, wo_bf, bo, out, MROWS, D_, K_);
}

// Round 4
// 426.542 us; speedup vs baseline: 4.3829x; 1.0428x over previous
//
#include <hip/hip_runtime.h>

typedef __attribute__((ext_vector_type(8))) __bf16 bf16x8;
typedef __attribute__((ext_vector_type(4))) float f32x4;
typedef __attribute__((ext_vector_type(4))) unsigned int uint4v;

#define B_ 16
#define S_ 577
#define D_ 1408
#define H_ 16
#define HD_ 88
#define MROWS (B_*S_)   // 9232
#define N1 (3*D_)       // 4224
#define K_ D_           // 1408
#define KSTEPS 44       // 1408/32
#define VT_LD 592
#define SCALE 0.10660035817780521f

static __device__ __forceinline__ void async16(void* lds, const void* g) {
  __builtin_amdgcn_global_load_lds((const __attribute__((address_space(1))) void*)g,
                                   (__attribute__((address_space(3))) void*)lds, 16, 0, 0);
}

// bijective XCD-aware remap (m204): contiguous wgid chunk per XCD
static __device__ __forceinline__ int xcd_swizzle(int orig, int nwg) {
  int xcd = orig & 7, lid = orig >> 3;
  int q = nwg >> 3, r = nwg & 7;
  return (xcd < r ? xcd * (q + 1) : r * (q + 1) + (xcd - r) * q) + lid;
}

// ---------------- cast fp32 -> bf16 (vectorized) ----------------
__global__ void cast_bf16_kernel(const float* __restrict__ src, __bf16* __restrict__ dst, int n4) {
  int i = blockIdx.x * blockDim.x + threadIdx.x;
  if (i >= n4) return;
  const float4 v = ((const float4*)src)[i];
  __bf16* d = dst + (size_t)i * 4;
  d[0] = (__bf16)v.x; d[1] = (__bf16)v.y; d[2] = (__bf16)v.z; d[3] = (__bf16)v.w;
}

// ---------------- GEMM1: qkv = x @ Wqkv^T + b, fused RoPE+split+permute ----------------
// 128x128 tile, BK=32, 2-phase dbuf (stage t+1 before compute t, 1 barrier/K-step),
// bijective XCD swizzle (M-fastest: each XCD owns ~4 N-cols -> B panels L2-resident).
__launch_bounds__(256, 2)
__global__ void gemm_qkv_rope(const __bf16* __restrict__ A, const __bf16* __restrict__ Bm,
                              const float* __restrict__ bias, const float* __restrict__ freqs,
                              __bf16* __restrict__ Qb, __bf16* __restrict__ Kb,
                              __bf16* __restrict__ Vb) {
  __shared__ __bf16 As[2][128 * 32];
  __shared__ __bf16 Bs[2][128 * 32];
  const int tid = threadIdx.x;
  const int w = tid >> 6, l = tid & 63;
  const int wgid = xcd_swizzle(blockIdx.x, 33 * 73);
  const int m0 = (wgid % 73) * 128, n0 = (wgid / 73) * 128;
  const int wr = w & 1, wc = w >> 1;
  const int M = MROWS, K = K_;

  f32x4 acc[4][4];
#pragma unroll
  for (int m = 0; m < 4; ++m)
#pragma unroll
    for (int n = 0; n < 4; ++n) acc[m][n] = (f32x4){0.f, 0.f, 0.f, 0.f};

  int arow0 = m0 + w * 32 + (l >> 2);      if (arow0 >= M) arow0 = M - 1;
  int arow1 = m0 + w * 32 + 16 + (l >> 2); if (arow1 >= M) arow1 = M - 1;
  const __bf16* ag0 = A + (size_t)arow0 * K + (l & 3) * 8;
  const __bf16* ag1 = A + (size_t)arow1 * K + (l & 3) * 8;
  const __bf16* bg0 = Bm + (size_t)(n0 + w * 32 + (l >> 2)) * K + (l & 3) * 8;
  const __bf16* bg1 = Bm + (size_t)(n0 + w * 32 + 16 + (l >> 2)) * K + (l & 3) * 8;

  auto stage = [&](int buf, int k0) {
    async16(&As[buf][(w * 32) * 32],      ag0 + k0);
    async16(&As[buf][(w * 32 + 16) * 32], ag1 + k0);
    async16(&Bs[buf][(w * 32) * 32],      bg0 + k0);
    async16(&Bs[buf][(w * 32 + 16) * 32], bg1 + k0);
  };

  stage(0, 0);
  __syncthreads();
  for (int t = 0; t < KSTEPS; ++t) {
    const int cur = t & 1;
    if (t < KSTEPS - 1) stage(cur ^ 1, (t + 1) * 32);
    bf16x8 a[4], b[4];
#pragma unroll
    for (int m = 0; m < 4; ++m)
      a[m] = *(const bf16x8*)&As[cur][(wr * 64 + m * 16 + (l & 15)) * 32 + (l >> 4) * 8];
#pragma unroll
    for (int n = 0; n < 4; ++n)
      b[n] = *(const bf16x8*)&Bs[cur][(wc * 64 + n * 16 + (l & 15)) * 32 + (l >> 4) * 8];
#pragma unroll
    for (int m = 0; m < 4; ++m)
#pragma unroll
      for (int n = 0; n < 4; ++n)
        acc[m][n] = __builtin_amdgcn_mfma_f32_16x16x32_bf16(a[m], b[n], acc[m][n], 0, 0, 0);
    __syncthreads();
  }

  const int sect = n0 / 1408;  // 0=q 1=k 2=v, uniform per block
  __bf16* dst = (sect == 0) ? Qb : (sect == 1 ? Kb : Vb);
#pragma unroll
  for (int n = 0; n < 4; ++n) {
    const int col = n0 + wc * 64 + n * 16 + (l & 15);
    const int cin = col - sect * 1408;
    const int h = cin / 88, d = cin % 88;
    const float bv = bias[col];
    const int i2 = d & ~1;
    const float sgn = (d & 1) ? 1.f : -1.f;
#pragma unroll
    for (int m = 0; m < 4; ++m) {
      const int rbase = m0 + wr * 64 + m * 16 + (l >> 4) * 4;
#pragma unroll
      for (int j = 0; j < 4; ++j) {
        const int r = rbase + j;
        float val = acc[m][n][j] + bv;
        const int s = r % 577;
        float outv;
        if (sect < 2) {
          const float2 cs = *(const float2*)&freqs[s * 88 + i2];
          const float p = __shfl_xor(val, 1);
          outv = val * cs.x + sgn * p * cs.y;
        } else {
          outv = val;
        }
        if (r < M) {
          const int b = r / 577;
          dst[((size_t)(b * 16 + h) * 577 + s) * 88 + d] = (__bf16)outv;
        }
      }
    }
  }
}

// ---------------- GEMM2: out = ctx @ Wo^T + bo (fp32 out), same 2-phase loop ----------------
__launch_bounds__(256, 2)
__global__ void gemm_out_bias(const __bf16* __restrict__ A, const __bf16* __restrict__ Bm,
                              const float* __restrict__ bias, float* __restrict__ C) {
  __shared__ __bf16 As[2][128 * 32];
  __shared__ __bf16 Bs[2][128 * 32];
  const int tid = threadIdx.x;
  const int w = tid >> 6, l = tid & 63;
  const int wgid = xcd_swizzle(blockIdx.x, 11 * 73);
  const int m0 = (wgid % 73) * 128, n0 = (wgid / 73) * 128;
  const int wr = w & 1, wc = w >> 1;
  const int M = MROWS, N = D_, K = K_;

  f32x4 acc[4][4];
#pragma unroll
  for (int m = 0; m < 4; ++m)
#pragma unroll
    for (int n = 0; n < 4; ++n) acc[m][n] = (f32x4){0.f, 0.f, 0.f, 0.f};

  int arow0 = m0 + w * 32 + (l >> 2);      if (arow0 >= M) arow0 = M - 1;
  int arow1 = m0 + w * 32 + 16 + (l >> 2); if (arow1 >= M) arow1 = M - 1;
  const __bf16* ag0 = A + (size_t)arow0 * K + (l & 3) * 8;
  const __bf16* ag1 = A + (size_t)arow1 * K + (l & 3) * 8;
  const __bf16* bg0 = Bm + (size_t)(n0 + w * 32 + (l >> 2)) * K + (l & 3) * 8;
  const __bf16* bg1 = Bm + (size_t)(n0 + w * 32 + 16 + (l >> 2)) * K + (l & 3) * 8;

  auto stage = [&](int buf, int k0) {
    async16(&As[buf][(w * 32) * 32],      ag0 + k0);
    async16(&As[buf][(w * 32 + 16) * 32], ag1 + k0);
    async16(&Bs[buf][(w * 32) * 32],      bg0 + k0);
    async16(&Bs[buf][(w * 32 + 16) * 32], bg1 + k0);
  };

  stage(0, 0);
  __syncthreads();
  for (int t = 0; t < KSTEPS; ++t) {
    const int cur = t & 1;
    if (t < KSTEPS - 1) stage(cur ^ 1, (t + 1) * 32);
    bf16x8 a[4], b[4];
#pragma unroll
    for (int m = 0; m < 4; ++m)
      a[m] = *(const bf16x8*)&As[cur][(wr * 64 + m * 16 + (l & 15)) * 32 + (l >> 4) * 8];
#pragma unroll
    for (int n = 0; n < 4; ++n)
      b[n] = *(const bf16x8*)&Bs[cur][(wc * 64 + n * 16 + (l & 15)) * 32 + (l >> 4) * 8];
#pragma unroll
    for (int m = 0; m < 4; ++m)
#pragma unroll
      for (int n = 0; n < 4; ++n)
        acc[m][n] = __builtin_amdgcn_mfma_f32_16x16x32_bf16(a[m], b[n], acc[m][n], 0, 0, 0);
    __syncthreads();
  }

#pragma unroll
  for (int n = 0; n < 4; ++n) {
    int col = n0 + wc * 64 + n * 16 + (l & 15);
    float bv = bias[col];
#pragma unroll
    for (int m = 0; m < 4; ++m) {
      int rbase = m0 + wr * 64 + m * 16 + (l >> 4) * 4;
#pragma unroll
      for (int j = 0; j < 4; ++j) {
        int r = rbase + j;
        if (r < M) C[(size_t)r * N + col] = acc[m][n][j] + bv;
      }
    }
  }
}

// ---------------- V transpose: v_bf [bh][577][88] -> Vt_g [bh][88][592] ----------------
__global__ void transpose_v(const __bf16* __restrict__ V, __bf16* __restrict__ Vt_g) {
  __shared__ __bf16 Ls[64 * 104];
  const int bh = blockIdx.x, t = blockIdx.y, s0 = t * 64;
  const int tid = threadIdx.x;
  const __bf16* vp = V + (size_t)bh * 577 * 88;
  for (int i = tid; i < 64 * 11; i += 256) {
    int r = i / 11, off = i % 11;
    int gs = s0 + r; if (gs > 576) gs = 576;
    *(uint4v*)&Ls[r * 104 + off * 8] = *(const uint4v*)(vp + (size_t)gs * 88 + off * 8);
  }
  __syncthreads();
  for (int i = tid; i < 88 * 8; i += 256) {
    int d = i / 8, so = (i % 8) * 8;
    int sc_ = s0 + so;
    if (sc_ < VT_LD) {
      __bf16 tmp[8];
#pragma unroll
      for (int j = 0; j < 8; ++j) tmp[j] = Ls[(so + j) * 104 + d];
      *(uint4v*)&Vt_g[((size_t)bh * 88 + d) * VT_LD + sc_] = *(uint4v*)tmp;
    }
  }
}

// ---------------- flash attention: block = (bh, 128 q-rows), 4 waves x 32 rows ----------------
__launch_bounds__(256, 3)
__global__ void attn_kernel(const __bf16* __restrict__ Q, const __bf16* __restrict__ K,
                            const __bf16* __restrict__ Vt_gp, __bf16* __restrict__ ctx) {
  __shared__ __bf16 lds[26368];
  const int tid = threadIdx.x;
  const int w = tid >> 6, l = tid & 63;
  const int bh = blockIdx.x;
  const int q0 = blockIdx.y * 128;
  const __bf16* qp = Q + (size_t)bh * 577 * 88;
  const __bf16* kp = K + (size_t)bh * 577 * 88;
  const __bf16* vtp = Vt_gp + (size_t)bh * 88 * VT_LD;
  __bf16* Qs = lds;             // [128][96]
  __bf16* Ks = lds + 12288;     // [64][88]
  __bf16* Vt = lds + 17920;     // [96][88]
  __bf16* Pw = lds + w * 2304;  // per-wave P [32][72]

  for (int i = tid; i < 128 * 11; i += 256) {
    int r = i / 11, off = i % 11;
    int gr = q0 + r; if (gr > 576) gr = 576;
    *(uint4v*)&Qs[r * 96 + off * 8] = *(const uint4v*)(qp + (size_t)gr * 88 + off * 8);
  }
  if (tid < 128) { uint4v z = 0; *(uint4v*)&Qs[tid * 96 + 88] = z; }
  __syncthreads();

  bf16x8 qf[2][3];
#pragma unroll
  for (int mg = 0; mg < 2; ++mg)
#pragma unroll
    for (int kk = 0; kk < 3; ++kk)
      qf[mg][kk] = *(const bf16x8*)&Qs[(w * 32 + mg * 16 + (l & 15)) * 96 + kk * 32 + (l >> 4) * 8];

  int preA[7], preB[7];
#pragma unroll
  for (int kch = 0; kch < 7; ++kch) {
    int c = w + 4 * kch;
    int a = 0, b2 = 0;
    if (c < 11) a = c * 512 + l * 8;
    else if (c < 27) { int e = (c - 11) * 512 + l * 8; a = (e / 88) * VT_LD; b2 = e % 88; }
    preA[kch] = a; preB[kch] = b2;
  }

  f32x4 oacc[2][6];
#pragma unroll
  for (int mg = 0; mg < 2; ++mg)
#pragma unroll
    for (int dn = 0; dn < 6; ++dn) oacc[mg][dn] = (f32x4){0.f, 0.f, 0.f, 0.f};
  f32x4 mrun[2], lrun[2];
  mrun[0] = -1e30f; mrun[1] = -1e30f;
  lrun[0] = 0.f; lrun[1] = 0.f;

  for (int t = 0; t < 10; ++t) {
    const int s0 = t * 64;
    if (t) __syncthreads();
#pragma unroll
    for (int kch = 0; kch < 7; ++kch) {
      int c = w + 4 * kch;
      if (c < 11) {
        async16(Ks + c * 512, kp + (size_t)s0 * 88 + preA[kch]);
      } else if (c < 27) {
        int g = s0 + preB[kch]; if (g > 584) g = 584;
        async16(Vt + (c - 11) * 512, vtp + preA[kch] + g);
      }
    }
    __syncthreads();

    f32x4 sc[2][4];
#pragma unroll
    for (int mg = 0; mg < 2; ++mg)
#pragma unroll
      for (int n = 0; n < 4; ++n) sc[mg][n] = (f32x4){0.f, 0.f, 0.f, 0.f};
#pragma unroll
    for (int n = 0; n < 4; ++n) {
#pragma unroll
      for (int kk = 0; kk < 3; ++kk) {
        bf16x8 kf = *(const bf16x8*)&Ks[(n * 16 + (l & 15)) * 88 + kk * 32 + (l >> 4) * 8];
        sc[0][n] = __builtin_amdgcn_mfma_f32_16x16x32_bf16(qf[0][kk], kf, sc[0][n], 0, 0, 0);
        sc[1][n] = __builtin_amdgcn_mfma_f32_16x16x32_bf16(qf[1][kk], kf, sc[1][n], 0, 0, 0);
      }
    }

    f32x4 tmax[2];
    tmax[0] = -1e30f; tmax[1] = -1e30f;
#pragma unroll
    for (int n = 0; n < 4; ++n) {
      const int kc = s0 + n * 16 + (l & 15);
      const bool valid = kc < 577;
#pragma unroll
      for (int mg = 0; mg < 2; ++mg)
#pragma unroll
        for (int j = 0; j < 4; ++j) {
          float v = valid ? sc[mg][n][j] * SCALE : -1e30f;
          sc[mg][n][j] = v;
          tmax[mg][j] = fmaxf(tmax[mg][j], v);
        }
    }
#pragma unroll
    for (int o = 1; o < 16; o <<= 1)
#pragma unroll
      for (int mg = 0; mg < 2; ++mg)
#pragma unroll
        for (int j = 0; j < 4; ++j)
          tmax[mg][j] = fmaxf(tmax[mg][j], __shfl_xor(tmax[mg][j], o));
#pragma unroll
    for (int mg = 0; mg < 2; ++mg)
#pragma unroll
      for (int j = 0; j < 4; ++j) {
        float mo = mrun[mg][j];
        float mn = fmaxf(mo, tmax[mg][j]);
        float sf = __expf(mo - mn);
        mrun[mg][j] = mn;
        lrun[mg][j] *= sf;
#pragma unroll
        for (int dn = 0; dn < 6; ++dn) oacc[mg][dn][j] *= sf;
      }
#pragma unroll
    for (int mg = 0; mg < 2; ++mg)
#pragma unroll
      for (int n = 0; n < 4; ++n)
#pragma unroll
        for (int j = 0; j < 4; ++j) {
          float p = __expf(sc[mg][n][j] - mrun[mg][j]);
          lrun[mg][j] += p;
          Pw[(mg * 16 + (l >> 4) * 4 + j) * 72 + n * 16 + (l & 15)] = (__bf16)p;
        }

#pragma unroll
    for (int ks = 0; ks < 2; ++ks) {
      bf16x8 pa0 = *(const bf16x8*)&Pw[((l & 15)) * 72 + ks * 32 + (l >> 4) * 8];
      bf16x8 pa1 = *(const bf16x8*)&Pw[(16 + (l & 15)) * 72 + ks * 32 + (l >> 4) * 8];
#pragma unroll
      for (int dn = 0; dn < 6; ++dn) {
        bf16x8 vb = *(const bf16x8*)&Vt[(dn * 16 + (l & 15)) * 88 + ks * 32 + (l >> 4) * 8];
        oacc[0][dn] = __builtin_amdgcn_mfma_f32_16x16x32_bf16(pa0, vb, oacc[0][dn], 0, 0, 0);
        oacc[1][dn] = __builtin_amdgcn_mfma_f32_16x16x32_bf16(pa1, vb, oacc[1][dn], 0, 0, 0);
      }
    }
  }

#pragma unroll
  for (int o = 1; o < 16; o <<= 1)
#pragma unroll
    for (int mg = 0; mg < 2; ++mg)
#pragma unroll
      for (int j = 0; j < 4; ++j)
        lrun[mg][j] += __shfl_xor(lrun[mg][j], o);

  const int b = bh >> 4, h = bh & 15;
#pragma unroll
  for (int mg = 0; mg < 2; ++mg) {
    float inv[4];
#pragma unroll
    for (int j = 0; j < 4; ++j) inv[j] = 1.f / lrun[mg][j];
    const int sqb = q0 + w * 32 + mg * 16 + (l >> 4) * 4;
#pragma unroll
    for (int dn = 0; dn < 6; ++dn) {
      const int d = dn * 16 + (l & 15);
      if (d >= 88) continue;
#pragma unroll
      for (int j = 0; j < 4; ++j) {
        const int sq = sqb + j;
        if (sq < 577)
          ctx[((size_t)(b * 577 + sq)) * 1408 + h * 88 + d] = (__bf16)(oacc[mg][dn][j] * inv[j]);
      }
    }
  }
}

extern "C" void kernel_launch(void* const* d_in, const int* in_sizes, int n_in,
                              void* d_out, int out_size, void* d_ws, size_t ws_size,
                              hipStream_t stream) {
  const float* hs    = (const float*)d_in[0];
  const float* freqs = (const float*)d_in[1];
  const float* wqkv  = (const float*)d_in[2];
  const float* bqkv  = (const float*)d_in[3];
  const float* wo    = (const float*)d_in[4];
  const float* bo    = (const float*)d_in[5];
  float* out = (float*)d_out;

  char* ws = (char*)d_ws;
  size_t off = 0;
  auto alloc = [&](size_t bytes) {
    void* p = ws + off;
    off += (bytes + 255) & ~(size_t)255;
    return p;
  };
  __bf16* x_bf    = (__bf16*)alloc((size_t)MROWS * K_ * 2);
  __bf16* ctx_bf  = x_bf;  // aliased: x dead after GEMM1
  __bf16* wqkv_bf = (__bf16*)alloc((size_t)N1 * K_ * 2);
  __bf16* wo_bf   = (__bf16*)alloc((size_t)D_ * K_ * 2);
  __bf16* q_bf    = (__bf16*)alloc((size_t)MROWS * D_ * 2);
  __bf16* k_bf    = (__bf16*)alloc((size_t)MROWS * D_ * 2);
  __bf16* v_bf    = (__bf16*)alloc((size_t)MROWS * D_ * 2);
  __bf16* vt_g    = (__bf16*)d_out;  // V^T scratch in d_out; GEMM2 overwrites later

  cast_bf16_kernel<<<(MROWS * K_ / 4 + 255) / 256, 256, 0, stream>>>(hs, x_bf, MROWS * K_ / 4);
  cast_bf16_kernel<<<(N1 * K_ / 4 + 255) / 256, 256, 0, stream>>>(wqkv, wqkv_bf, N1 * K_ / 4);
  cast_bf16_kernel<<<(D_ * K_ / 4 + 255) / 256, 256, 0, stream>>>(wo, wo_bf, D_ * K_ / 4);

  gemm_qkv_rope<<<33 * 73, 256, 0, stream>>>(x_bf, wqkv_bf, bqkv, freqs, q_bf, k_bf, v_bf);

  transpose_v<<<dim3(256, 10), 256, 0, stream>>>(v_bf, vt_g);

  attn_kernel<<<dim3(256, 5), 256, 0, stream>>>(q_bf, k_bf, vt_g, ctx_bf);

  gemm_out_bias<<<11 * 73, 256, 0, stream>>>(ctx_bf, wo_bf, bo, out);
}

// Round 5
// 422.856 us; speedup vs baseline: 4.4211x; 1.0087x over previous
//
#include <hip/hip_runtime.h>

typedef __attribute__((ext_vector_type(8))) __bf16 bf16x8;
typedef __attribute__((ext_vector_type(4))) float f32x4;
typedef __attribute__((ext_vector_type(4))) unsigned int uint4v;

#define B_ 16
#define S_ 577
#define D_ 1408
#define H_ 16
#define HD_ 88
#define MROWS (B_*S_)   // 9232
#define N1 (3*D_)       // 4224
#define K_ D_           // 1408
#define VT_LD 592
#define SCALE 0.10660035817780521f

static __device__ __forceinline__ void async16(void* lds, const void* g) {
  __builtin_amdgcn_global_load_lds((const __attribute__((address_space(1))) void*)g,
                                   (__attribute__((address_space(3))) void*)lds, 16, 0, 0);
}

// bijective XCD-aware remap (m204): contiguous wgid chunk per XCD
static __device__ __forceinline__ int xcd_swizzle(int orig, int nwg) {
  int xcd = orig & 7, lid = orig >> 3;
  int q = nwg >> 3, r = nwg & 7;
  return (xcd < r ? xcd * (q + 1) : r * (q + 1) + (xcd - r) * q) + lid;
}

#define LGKM0() do { asm volatile("s_waitcnt lgkmcnt(0)" ::: "memory"); \
                     __builtin_amdgcn_sched_barrier(0); } while (0)
#define VMDRAIN() asm volatile("s_waitcnt vmcnt(0)" ::: "memory")
#define BARR() __builtin_amdgcn_s_barrier()

// ---------------- cast fp32 -> bf16 (vectorized) ----------------
__global__ void cast_bf16_kernel(const float* __restrict__ src, __bf16* __restrict__ dst, int n4) {
  int i = blockIdx.x * blockDim.x + threadIdx.x;
  if (i >= n4) return;
  const float4 v = ((const float4*)src)[i];
  __bf16* d = dst + (size_t)i * 4;
  d[0] = (__bf16)v.x; d[1] = (__bf16)v.y; d[2] = (__bf16)v.z; d[3] = (__bf16)v.w;
}

// ================= 256x256 8-phase GEMM core (BK=64, 8 waves 2Mx4N) =================
// LDS: buf b at elems b*32768: A [256][64] then B [256][64]. T2 swizzle:
// LDS[row][c] holds global col-slot (c ^ (row&7)) (8-elem slots); gload_lds dest
// linear, source col-slot = (l&7)^(l>>3); frag reads XOR (row&7).
__device__ __forceinline__ void gemm256_core(const __bf16* __restrict__ A,
                                             const __bf16* __restrict__ Bm,
                                             int m0, int n0, int Arows, int Brows,
                                             __bf16* lds, f32x4 (&acc)[8][4]) {
  const int tid = threadIdx.x;
  const int w = tid >> 6, l = tid & 63;
  const int wm = w >> 2, wn = w & 3;
  const int l15 = l & 15;
  const int x0 = (((l >> 4) * 8)) ^ ((l & 7) << 3);       // kk=0 frag col elems
  const int x1 = ((32 + (l >> 4) * 8)) ^ ((l & 7) << 3);  // kk=1
  const int sbase = w * 512;                               // stage dest elems (1KB/wave)

  // staging source pointers [half][round]
  const int lr = w * 8 + (l >> 3);
  const int swc = ((l & 7) ^ (l >> 3)) * 8;
  const __bf16* pa[2][2];
  const __bf16* pb[2][2];
#pragma unroll
  for (int h = 0; h < 2; ++h)
#pragma unroll
    for (int r8 = 0; r8 < 2; ++r8) {
      int ra = m0 + h * 128 + r8 * 64 + lr; if (ra >= Arows) ra = Arows - 1;
      int rb = n0 + h * 128 + r8 * 64 + lr; if (rb >= Brows) rb = Brows - 1;
      pa[h][r8] = A + (size_t)ra * K_ + swc;
      pb[h][r8] = Bm + (size_t)rb * K_ + swc;
    }

#pragma unroll
  for (int m = 0; m < 8; ++m)
#pragma unroll
    for (int n = 0; n < 4; ++n) acc[m][n] = (f32x4){0.f, 0.f, 0.f, 0.f};

  // prologue: stage K-tile 0 into buf0 (A then B)
#pragma unroll
  for (int h = 0; h < 2; ++h)
#pragma unroll
    for (int r8 = 0; r8 < 2; ++r8) {
      async16(lds + h * 8192 + r8 * 4096 + sbase, pa[h][r8]);
      async16(lds + 16384 + h * 8192 + r8 * 4096 + sbase, pb[h][r8]);
    }
  VMDRAIN();
  BARR();

  bf16x8 af[4][2], bfr[2][2];

#define RD_A(MH) { _Pragma("unroll") for (int i = 0; i < 4; ++i) { \
    const __bf16* rp = At + (wm * 128 + (MH) * 64 + i * 16 + l15) * 64; \
    af[i][0] = *(const bf16x8*)(rp + x0); af[i][1] = *(const bf16x8*)(rp + x1); } }
#define RD_B(NH) { _Pragma("unroll") for (int jn = 0; jn < 2; ++jn) { \
    const __bf16* rp = Bt + (wn * 64 + (NH) * 32 + jn * 16 + l15) * 64; \
    bfr[jn][0] = *(const bf16x8*)(rp + x0); bfr[jn][1] = *(const bf16x8*)(rp + x1); } }
#define MM(MH, NH) { __builtin_amdgcn_s_setprio(1); \
    _Pragma("unroll") for (int i = 0; i < 4; ++i) _Pragma("unroll") for (int jn = 0; jn < 2; ++jn) { \
      acc[(MH)*4+i][(NH)*2+jn] = __builtin_amdgcn_mfma_f32_16x16x32_bf16(af[i][0], bfr[jn][0], acc[(MH)*4+i][(NH)*2+jn], 0, 0, 0); \
      acc[(MH)*4+i][(NH)*2+jn] = __builtin_amdgcn_mfma_f32_16x16x32_bf16(af[i][1], bfr[jn][1], acc[(MH)*4+i][(NH)*2+jn], 0, 0, 0); } \
    __builtin_amdgcn_s_setprio(0); }
#define STG(WHICH, PP, KC) { _Pragma("unroll") for (int h = 0; h < 2; ++h) \
    _Pragma("unroll") for (int r8 = 0; r8 < 2; ++r8) \
      async16(Sd + (WHICH) * 16384 + h * 8192 + r8 * 4096 + sbase, PP[h][r8] + (KC)); }

  for (int kt = 0; kt < 21; ++kt) {
    __bf16* At = lds + (kt & 1) * 32768;
    __bf16* Bt = At + 16384;
    __bf16* Sd = lds + ((kt & 1) ^ 1) * 32768;
    const int kc = (kt + 1) * 64;
    // phase 1: (mh0, nh0); stage next A
    RD_A(0); RD_B(0);
    STG(0, pa, kc);
    BARR(); LGKM0();
    MM(0, 0);
    BARR();
    // phase 2: (mh1, nh0); stage next B
    RD_A(1);
    STG(1, pb, kc);
    BARR(); LGKM0();
    MM(1, 0);
    BARR();
    // phase 3: (mh1, nh1)
    RD_B(1);
    BARR(); LGKM0();
    MM(1, 1);
    BARR();
    // phase 4: (mh0, nh1); drain (loads are 2-3 phases old)
    RD_A(0);
    BARR(); LGKM0();
    MM(0, 1);
    VMDRAIN();
    BARR();
  }
  // peeled last K-tile (kt = 21, buf1, no staging)
  {
    __bf16* At = lds + 32768;
    __bf16* Bt = At + 16384;
    RD_A(0); RD_B(0);
    BARR(); LGKM0();
    MM(0, 0);
    BARR();
    RD_A(1);
    BARR(); LGKM0();
    MM(1, 0);
    BARR();
    RD_B(1);
    BARR(); LGKM0();
    MM(1, 1);
    BARR();
    RD_A(0);
    BARR(); LGKM0();
    MM(0, 1);
  }
#undef RD_A
#undef RD_B
#undef MM
#undef STG
}

// ---------------- GEMM1: qkv = x @ Wqkv^T + b, fused RoPE+split+permute ----------------
__launch_bounds__(512, 2)
__global__ void gemm_qkv_rope(const __bf16* __restrict__ A, const __bf16* __restrict__ Bm,
                              const float* __restrict__ bias, const float* __restrict__ freqs,
                              __bf16* __restrict__ Qb, __bf16* __restrict__ Kb,
                              __bf16* __restrict__ Vb) {
  __shared__ __align__(16) __bf16 lds[65536];
  const int wgid = xcd_swizzle(blockIdx.x, 37 * 17);
  const int m0 = (wgid % 37) * 256, n0 = (wgid / 37) * 256;
  f32x4 acc[8][4];
  gemm256_core(A, Bm, m0, n0, MROWS, N1, lds, acc);

  const int tid = threadIdx.x;
  const int w = tid >> 6, l = tid & 63;
  const int wm = w >> 2, wn = w & 3;
#pragma unroll
  for (int n = 0; n < 4; ++n) {
    const int col = n0 + wn * 64 + n * 16 + (l & 15);
    if (col >= N1) continue;  // wave-uniform: frag boundaries are multiples of 16
    const int sect = col / 1408;
    const int cin = col - sect * 1408;
    const int h = cin / 88, d = cin - h * 88;
    const float bv = bias[col];
    const float sgn = (d & 1) ? 1.f : -1.f;
    const int i2 = d & ~1;
    __bf16* dst = (sect == 0) ? Qb : (sect == 1 ? Kb : Vb);
#pragma unroll
    for (int m = 0; m < 8; ++m) {
      const int rb = m0 + wm * 128 + m * 16 + (l >> 4) * 4;
#pragma unroll
      for (int j = 0; j < 4; ++j) {
        const int r = rb + j;
        float val = acc[m][n][j] + bv;
        const int s = r % 577;
        float outv = val;
        if (sect < 2) {
          const float2 cs = *(const float2*)&freqs[s * 88 + i2];
          const float p = __shfl_xor(val, 1);
          outv = val * cs.x + sgn * p * cs.y;
        }
        if (r < MROWS) {
          const int b = r / 577;
          dst[((size_t)(b * 16 + h) * 577 + s) * 88 + d] = (__bf16)outv;
        }
      }
    }
  }
}

// ---------------- GEMM2: out = ctx @ Wo^T + bo (fp32 out) ----------------
__launch_bounds__(512, 2)
__global__ void gemm_out_bias(const __bf16* __restrict__ A, const __bf16* __restrict__ Bm,
                              const float* __restrict__ bias, float* __restrict__ C) {
  __shared__ __align__(16) __bf16 lds[65536];
  const int wgid = xcd_swizzle(blockIdx.x, 37 * 6);
  const int m0 = (wgid % 37) * 256, n0 = (wgid / 37) * 256;
  f32x4 acc[8][4];
  gemm256_core(A, Bm, m0, n0, MROWS, D_, lds, acc);

  const int tid = threadIdx.x;
  const int w = tid >> 6, l = tid & 63;
  const int wm = w >> 2, wn = w & 3;
#pragma unroll
  for (int n = 0; n < 4; ++n) {
    const int col = n0 + wn * 64 + n * 16 + (l & 15);
    if (col >= D_) continue;
    const float bv = bias[col];
#pragma unroll
    for (int m = 0; m < 8; ++m) {
      const int rb = m0 + wm * 128 + m * 16 + (l >> 4) * 4;
#pragma unroll
      for (int j = 0; j < 4; ++j) {
        const int r = rb + j;
        if (r < MROWS) C[(size_t)r * D_ + col] = acc[m][n][j] + bv;
      }
    }
  }
}

// ---------------- V transpose: v_bf [bh][577][88] -> Vt_g [bh][88][592] ----------------
__global__ void transpose_v(const __bf16* __restrict__ V, __bf16* __restrict__ Vt_g) {
  __shared__ __bf16 Ls[64 * 104];
  const int bh = blockIdx.x, t = blockIdx.y, s0 = t * 64;
  const int tid = threadIdx.x;
  const __bf16* vp = V + (size_t)bh * 577 * 88;
  for (int i = tid; i < 64 * 11; i += 256) {
    int r = i / 11, off = i % 11;
    int gs = s0 + r; if (gs > 576) gs = 576;
    *(uint4v*)&Ls[r * 104 + off * 8] = *(const uint4v*)(vp + (size_t)gs * 88 + off * 8);
  }
  __syncthreads();
  for (int i = tid; i < 88 * 8; i += 256) {
    int d = i / 8, so = (i % 8) * 8;
    int sc_ = s0 + so;
    if (sc_ < VT_LD) {
      __bf16 tmp[8];
#pragma unroll
      for (int j = 0; j < 8; ++j) tmp[j] = Ls[(so + j) * 104 + d];
      *(uint4v*)&Vt_g[((size_t)bh * 88 + d) * VT_LD + sc_] = *(uint4v*)tmp;
    }
  }
}

// ---------------- flash attention: block = (bh, 128 q-rows), 4 waves x 32 rows ----------------
__launch_bounds__(256, 3)
__global__ void attn_kernel(const __bf16* __restrict__ Q, const __bf16* __restrict__ K,
                            const __bf16* __restrict__ Vt_gp, __bf16* __restrict__ ctx) {
  __shared__ __bf16 lds[26368];
  const int tid = threadIdx.x;
  const int w = tid >> 6, l = tid & 63;
  const int bh = blockIdx.x;
  const int q0 = blockIdx.y * 128;
  const __bf16* qp = Q + (size_t)bh * 577 * 88;
  const __bf16* kp = K + (size_t)bh * 577 * 88;
  const __bf16* vtp = Vt_gp + (size_t)bh * 88 * VT_LD;
  __bf16* Qs = lds;             // [128][96]
  __bf16* Ks = lds + 12288;     // [64][88]
  __bf16* Vt = lds + 17920;     // [96][88]
  __bf16* Pw = lds + w * 2304;  // per-wave P [32][72]

  for (int i = tid; i < 128 * 11; i += 256) {
    int r = i / 11, off = i % 11;
    int gr = q0 + r; if (gr > 576) gr = 576;
    *(uint4v*)&Qs[r * 96 + off * 8] = *(const uint4v*)(qp + (size_t)gr * 88 + off * 8);
  }
  if (tid < 128) { uint4v z = 0; *(uint4v*)&Qs[tid * 96 + 88] = z; }
  __syncthreads();

  bf16x8 qf[2][3];
#pragma unroll
  for (int mg = 0; mg < 2; ++mg)
#pragma unroll
    for (int kk = 0; kk < 3; ++kk)
      qf[mg][kk] = *(const bf16x8*)&Qs[(w * 32 + mg * 16 + (l & 15)) * 96 + kk * 32 + (l >> 4) * 8];

  int preA[7], preB[7];
#pragma unroll
  for (int kch = 0; kch < 7; ++kch) {
    int c = w + 4 * kch;
    int a = 0, b2 = 0;
    if (c < 11) a = c * 512 + l * 8;
    else if (c < 27) { int e = (c - 11) * 512 + l * 8; a = (e / 88) * VT_LD; b2 = e % 88; }
    preA[kch] = a; preB[kch] = b2;
  }

  f32x4 oacc[2][6];
#pragma unroll
  for (int mg = 0; mg < 2; ++mg)
#pragma unroll
    for (int dn = 0; dn < 6; ++dn) oacc[mg][dn] = (f32x4){0.f, 0.f, 0.f, 0.f};
  f32x4 mrun[2], lrun[2];
  mrun[0] = -1e30f; mrun[1] = -1e30f;
  lrun[0] = 0.f; lrun[1] = 0.f;

  for (int t = 0; t < 10; ++t) {
    const int s0 = t * 64;
    if (t) __syncthreads();
#pragma unroll
    for (int kch = 0; kch < 7; ++kch) {
      int c = w + 4 * kch;
      if (c < 11) {
        async16(Ks + c * 512, kp + (size_t)s0 * 88 + preA[kch]);
      } else if (c < 27) {
        int g = s0 + preB[kch]; if (g > 584) g = 584;
        async16(Vt + (c - 11) * 512, vtp + preA[kch] + g);
      }
    }
    __syncthreads();

    f32x4 sc[2][4];
#pragma unroll
    for (int mg = 0; mg < 2; ++mg)
#pragma unroll
      for (int n = 0; n < 4; ++n) sc[mg][n] = (f32x4){0.f, 0.f, 0.f, 0.f};
#pragma unroll
    for (int n = 0; n < 4; ++n) {
#pragma unroll
      for (int kk = 0; kk < 3; ++kk) {
        bf16x8 kf = *(const bf16x8*)&Ks[(n * 16 + (l & 15)) * 88 + kk * 32 + (l >> 4) * 8];
        sc[0][n] = __builtin_amdgcn_mfma_f32_16x16x32_bf16(qf[0][kk], kf, sc[0][n], 0, 0, 0);
        sc[1][n] = __builtin_amdgcn_mfma_f32_16x16x32_bf16(qf[1][kk], kf, sc[1][n], 0, 0, 0);
      }
    }

    f32x4 tmax[2];
    tmax[0] = -1e30f; tmax[1] = -1e30f;
#pragma unroll
    for (int n = 0; n < 4; ++n) {
      const int kc = s0 + n * 16 + (l & 15);
      const bool valid = kc < 577;
#pragma unroll
      for (int mg = 0; mg < 2; ++mg)
#pragma unroll
        for (int j = 0; j < 4; ++j) {
          float v = valid ? sc[mg][n][j] * SCALE : -1e30f;
          sc[mg][n][j] = v;
          tmax[mg][j] = fmaxf(tmax[mg][j], v);
        }
    }
#pragma unroll
    for (int o = 1; o < 16; o <<= 1)
#pragma unroll
      for (int mg = 0; mg < 2; ++mg)
#pragma unroll
        for (int j = 0; j < 4; ++j)
          tmax[mg][j] = fmaxf(tmax[mg][j], __shfl_xor(tmax[mg][j], o));
#pragma unroll
    for (int mg = 0; mg < 2; ++mg)
#pragma unroll
      for (int j = 0; j < 4; ++j) {
        float mo = mrun[mg][j];
        float mn = fmaxf(mo, tmax[mg][j]);
        float sf = __expf(mo - mn);
        mrun[mg][j] = mn;
        lrun[mg][j] *= sf;
#pragma unroll
        for (int dn = 0; dn < 6; ++dn) oacc[mg][dn][j] *= sf;
      }
#pragma unroll
    for (int mg = 0; mg < 2; ++mg)
#pragma unroll
      for (int n = 0; n < 4; ++n)
#pragma unroll
        for (int j = 0; j < 4; ++j) {
          float p = __expf(sc[mg][n][j] - mrun[mg][j]);
          lrun[mg][j] += p;
          Pw[(mg * 16 + (l >> 4) * 4 + j) * 72 + n * 16 + (l & 15)] = (__bf16)p;
        }

#pragma unroll
    for (int ks = 0; ks < 2; ++ks) {
      bf16x8 pa0 = *(const bf16x8*)&Pw[((l & 15)) * 72 + ks * 32 + (l >> 4) * 8];
      bf16x8 pa1 = *(const bf16x8*)&Pw[(16 + (l & 15)) * 72 + ks * 32 + (l >> 4) * 8];
#pragma unroll
      for (int dn = 0; dn < 6; ++dn) {
        bf16x8 vb = *(const bf16x8*)&Vt[(dn * 16 + (l & 15)) * 88 + ks * 32 + (l >> 4) * 8];
        oacc[0][dn] = __builtin_amdgcn_mfma_f32_16x16x32_bf16(pa0, vb, oacc[0][dn], 0, 0, 0);
        oacc[1][dn] = __builtin_amdgcn_mfma_f32_16x16x32_bf16(pa1, vb, oacc[1][dn], 0, 0, 0);
      }
    }
  }

#pragma unroll
  for (int o = 1; o < 16; o <<= 1)
#pragma unroll
    for (int mg = 0; mg < 2; ++mg)
#pragma unroll
      for (int j = 0; j < 4; ++j)
        lrun[mg][j] += __shfl_xor(lrun[mg][j], o);

  const int b = bh >> 4, h = bh & 15;
#pragma unroll
  for (int mg = 0; mg < 2; ++mg) {
    float inv[4];
#pragma unroll
    for (int j = 0; j < 4; ++j) inv[j] = 1.f / lrun[mg][j];
    const int sqb = q0 + w * 32 + mg * 16 + (l >> 4) * 4;
#pragma unroll
    for (int dn = 0; dn < 6; ++dn) {
      const int d = dn * 16 + (l & 15);
      if (d >= 88) continue;
#pragma unroll
      for (int j = 0; j < 4; ++j) {
        const int sq = sqb + j;
        if (sq < 577)
          ctx[((size_t)(b * 577 + sq)) * 1408 + h * 88 + d] = (__bf16)(oacc[mg][dn][j] * inv[j]);
      }
    }
  }
}

extern "C" void kernel_launch(void* const* d_in, const int* in_sizes, int n_in,
                              void* d_out, int out_size, void* d_ws, size_t ws_size,
                              hipStream_t stream) {
  const float* hs    = (const float*)d_in[0];
  const float* freqs = (const float*)d_in[1];
  const float* wqkv  = (const float*)d_in[2];
  const float* bqkv  = (const float*)d_in[3];
  const float* wo    = (const float*)d_in[4];
  const float* bo    = (const float*)d_in[5];
  float* out = (float*)d_out;

  char* ws = (char*)d_ws;
  size_t off = 0;
  auto alloc = [&](size_t bytes) {
    void* p = ws + off;
    off += (bytes + 255) & ~(size_t)255;
    return p;
  };
  __bf16* x_bf    = (__bf16*)alloc((size_t)MROWS * K_ * 2);
  __bf16* ctx_bf  = x_bf;  // aliased: x dead after GEMM1
  __bf16* wqkv_bf = (__bf16*)alloc((size_t)N1 * K_ * 2);
  __bf16* wo_bf   = (__bf16*)alloc((size_t)D_ * K_ * 2);
  __bf16* q_bf    = (__bf16*)alloc((size_t)MROWS * D_ * 2);
  __bf16* k_bf    = (__bf16*)alloc((size_t)MROWS * D_ * 2);
  __bf16* v_bf    = (__bf16*)alloc((size_t)MROWS * D_ * 2);
  __bf16* vt_g    = (__bf16*)d_out;  // V^T scratch in d_out; GEMM2 overwrites later

  cast_bf16_kernel<<<(MROWS * K_ / 4 + 255) / 256, 256, 0, stream>>>(hs, x_bf, MROWS * K_ / 4);
  cast_bf16_kernel<<<(N1 * K_ / 4 + 255) / 256, 256, 0, stream>>>(wqkv, wqkv_bf, N1 * K_ / 4);
  cast_bf16_kernel<<<(D_ * K_ / 4 + 255) / 256, 256, 0, stream>>>(wo, wo_bf, D_ * K_ / 4);

  gemm_qkv_rope<<<37 * 17, 512, 0, stream>>>(x_bf, wqkv_bf, bqkv, freqs, q_bf, k_bf, v_bf);

  transpose_v<<<dim3(256, 10), 256, 0, stream>>>(v_bf, vt_g);

  attn_kernel<<<dim3(256, 5), 256, 0, stream>>>(q_bf, k_bf, vt_g, ctx_bf);

  gemm_out_bias<<<37 * 6, 512, 0, stream>>>(ctx_bf, wo_bf, bo, out);
}

// Round 8
// 421.457 us; speedup vs baseline: 4.4358x; 1.0033x over previous
//
#include <hip/hip_runtime.h>

typedef __attribute__((ext_vector_type(8))) __bf16 bf16x8;
typedef __attribute__((ext_vector_type(4))) float f32x4;
typedef __attribute__((ext_vector_type(4))) unsigned int uint4v;

#define B_ 16
#define S_ 577
#define D_ 1408
#define H_ 16
#define HD_ 88
#define MROWS (B_*S_)   // 9232
#define N1 (3*D_)       // 4224
#define K_ D_           // 1408
#define VT_LD 592
#define SCALE 0.10660035817780521f

static __device__ __forceinline__ void async16(void* lds, const void* g) {
  __builtin_amdgcn_global_load_lds((const __attribute__((address_space(1))) void*)g,
                                   (__attribute__((address_space(3))) void*)lds, 16, 0, 0);
}

// bijective XCD-aware remap (m204): contiguous wgid chunk per XCD
static __device__ __forceinline__ int xcd_swizzle(int orig, int nwg) {
  int xcd = orig & 7, lid = orig >> 3;
  int q = nwg >> 3, r = nwg & 7;
  return (xcd < r ? xcd * (q + 1) : r * (q + 1) + (xcd - r) * q) + lid;
}

#define SB0() __builtin_amdgcn_sched_barrier(0)
#define LGKM0() do { asm volatile("s_waitcnt lgkmcnt(0)" ::: "memory"); SB0(); } while (0)
#define VMW4()  do { asm volatile("s_waitcnt vmcnt(4)" ::: "memory"); SB0(); } while (0)
#define VMDRAIN() asm volatile("s_waitcnt vmcnt(0)" ::: "memory")
#define BARR() do { SB0(); __builtin_amdgcn_s_barrier(); SB0(); } while (0)

// ---------------- cast fp32 -> bf16 (vectorized) ----------------
__global__ void cast_bf16_kernel(const float* __restrict__ src, __bf16* __restrict__ dst, int n4) {
  int i = blockIdx.x * blockDim.x + threadIdx.x;
  if (i >= n4) return;
  const float4 v = ((const float4*)src)[i];
  __bf16* d = dst + (size_t)i * 4;
  d[0] = (__bf16)v.x; d[1] = (__bf16)v.y; d[2] = (__bf16)v.z; d[3] = (__bf16)v.w;
}

// ================= 256x256 GEMM core — quadrant-mapped 8-phase =================
// Per PHASE all 8 waves compute ONE C-quadrant (mh,nh): wave slab = rows
// mh*128+wm*64+[0,64), cols nh*128+wn*32+[0,32) (wm=w>>2, wn=w&3). Each phase
// reads exactly one A-half (mh) and one B-half (nh) -> half staging race-free
// with >=2-phase gaps. Stage slots: p1 A1(u+1)->other, p2 B0(u+1)->other,
// p3 A0(u+2)->cur, p4 B1(u+2)->cur; vmcnt(4) at p4 completes all of kt u+1.
__device__ __forceinline__ void gemm256_core(const __bf16* __restrict__ A,
                                             const __bf16* __restrict__ Bm,
                                             int m0, int n0, int Arows, int Brows,
                                             __bf16* lds, f32x4 (&acc)[8][4]) {
  const int tid = threadIdx.x;
  const int w = tid >> 6, l = tid & 63;
  const int wm = w >> 2, wn = w & 3;
  const int l15 = l & 15;
  const int x0 = ((l >> 4) * 8) ^ ((l & 7) << 3);
  const int x1 = (32 + (l >> 4) * 8) ^ ((l & 7) << 3);
  const int sbase = w * 512;

  const int lr = w * 8 + (l >> 3);
  const int swc = ((l & 7) ^ (l >> 3)) * 8;
  const __bf16* pa[2][2];
  const __bf16* pb[2][2];
#pragma unroll
  for (int h = 0; h < 2; ++h)
#pragma unroll
    for (int r8 = 0; r8 < 2; ++r8) {
      int ra = m0 + h * 128 + r8 * 64 + lr; if (ra >= Arows) ra = Arows - 1;
      int rb = n0 + h * 128 + r8 * 64 + lr; if (rb >= Brows) rb = Brows - 1;
      pa[h][r8] = A + (size_t)ra * K_ + swc;
      pb[h][r8] = Bm + (size_t)rb * K_ + swc;
    }

#pragma unroll
  for (int m = 0; m < 8; ++m)
#pragma unroll
    for (int n = 0; n < 4; ++n) acc[m][n] = (f32x4){0.f, 0.f, 0.f, 0.f};

  bf16x8 af[4][2], bfr[2][2];

#define STG_A(DB, H, KC) { async16(lds + (DB)*32768 + (H)*8192 + sbase, pa[H][0] + (KC)); \
                           async16(lds + (DB)*32768 + (H)*8192 + 4096 + sbase, pa[H][1] + (KC)); }
#define STG_B(DB, H, KC) { async16(lds + (DB)*32768 + 16384 + (H)*8192 + sbase, pb[H][0] + (KC)); \
                           async16(lds + (DB)*32768 + 16384 + (H)*8192 + 4096 + sbase, pb[H][1] + (KC)); }
#define RD_A(DB, MH) { _Pragma("unroll") for (int i = 0; i < 4; ++i) { \
    const __bf16* rp = lds + (DB)*32768 + ((MH) * 128 + wm * 64 + i * 16 + l15) * 64; \
    af[i][0] = *(const bf16x8*)(rp + x0); af[i][1] = *(const bf16x8*)(rp + x1); } }
#define RD_B(DB, NH) { _Pragma("unroll") for (int jn = 0; jn < 2; ++jn) { \
    const __bf16* rp = lds + (DB)*32768 + 16384 + ((NH) * 128 + wn * 32 + jn * 16 + l15) * 64; \
    bfr[jn][0] = *(const bf16x8*)(rp + x0); bfr[jn][1] = *(const bf16x8*)(rp + x1); } }
#define MM(MH, NH) { __builtin_amdgcn_s_setprio(1); \
    _Pragma("unroll") for (int i = 0; i < 4; ++i) _Pragma("unroll") for (int jn = 0; jn < 2; ++jn) { \
      acc[(MH)*4+i][(NH)*2+jn] = __builtin_amdgcn_mfma_f32_16x16x32_bf16(af[i][0], bfr[jn][0], acc[(MH)*4+i][(NH)*2+jn], 0, 0, 0); \
      acc[(MH)*4+i][(NH)*2+jn] = __builtin_amdgcn_mfma_f32_16x16x32_bf16(af[i][1], bfr[jn][1], acc[(MH)*4+i][(NH)*2+jn], 0, 0, 0); } \
    __builtin_amdgcn_s_setprio(0); }

  // prologue: kt0's 4 halves (8 loads, oldest) then A0(1), B1(1).
  STG_A(0, 0, 0); STG_B(0, 0, 0); STG_B(0, 1, 0); STG_A(0, 1, 0);
  SB0();
  STG_A(1, 0, 64); STG_B(1, 1, 64);
  VMW4();
  BARR();

  for (int u = 0; u < 22; ++u) {
    const int DB = u & 1, OD = DB ^ 1;
    const int kcN  = (u + 1 < 22) ? (u + 1) * 64 : 0;  // tail: dummy (counts exact)
    const int kcNN = (u + 2 < 22) ? (u + 2) * 64 : 0;
    // p1: quadrant (0,0)
    RD_A(DB, 0); RD_B(DB, 0);
    STG_A(OD, 1, kcN);
    BARR(); LGKM0();
    MM(0, 0);
    BARR();
    // p2: quadrant (0,1) — af reused
    RD_B(DB, 1);
    STG_B(OD, 0, kcN);
    BARR(); LGKM0();
    MM(0, 1);
    BARR();
    // p3: quadrant (1,1) — bfr reused
    RD_A(DB, 1);
    STG_A(DB, 0, kcNN);
    BARR(); LGKM0();
    MM(1, 1);
    BARR();
    // p4: quadrant (1,0) — af reused, B0 re-read
    RD_B(DB, 0);
    STG_B(DB, 1, kcNN);
    BARR(); LGKM0();
    MM(1, 0);
    VMW4();
    BARR();
  }
  VMDRAIN();
#undef STG_A
#undef STG_B
#undef RD_A
#undef RD_B
#undef MM
}

// ---------------- GEMM1: qkv = x @ Wqkv^T + b, fused RoPE+split+permute ----------------
__launch_bounds__(512, 2)
__global__ void gemm_qkv_rope(const __bf16* __restrict__ A, const __bf16* __restrict__ Bm,
                              const float* __restrict__ bias, const float* __restrict__ freqs,
                              __bf16* __restrict__ Qb, __bf16* __restrict__ Kb,
                              __bf16* __restrict__ Vb) {
  __shared__ __align__(16) __bf16 lds[65536];
  const int wgid = xcd_swizzle(blockIdx.x, 37 * 17);
  const int m0 = (wgid % 37) * 256, n0 = (wgid / 37) * 256;
  f32x4 acc[8][4];
  gemm256_core(A, Bm, m0, n0, MROWS, N1, lds, acc);

  const int tid = threadIdx.x;
  const int w = tid >> 6, l = tid & 63;
  const int wm = w >> 2, wn = w & 3;
#pragma unroll
  for (int n = 0; n < 4; ++n) {
    const int col = n0 + (n >> 1) * 128 + wn * 32 + (n & 1) * 16 + (l & 15);
    if (col >= N1) continue;
    const int sect = col / 1408;
    const int cin = col - sect * 1408;
    const int h = cin / 88, d = cin - h * 88;
    const float bv = bias[col];
    const float sgn = (d & 1) ? 1.f : -1.f;
    const int i2 = d & ~1;
    __bf16* dst = (sect == 0) ? Qb : (sect == 1 ? Kb : Vb);
#pragma unroll
    for (int m = 0; m < 8; ++m) {
      const int rb = m0 + (m >> 2) * 128 + wm * 64 + (m & 3) * 16 + (l >> 4) * 4;
#pragma unroll
      for (int j = 0; j < 4; ++j) {
        const int r = rb + j;
        float val = acc[m][n][j] + bv;
        const int s = r % 577;
        float outv = val;
        if (sect < 2) {
          const float2 cs = *(const float2*)&freqs[s * 88 + i2];
          const float p = __shfl_xor(val, 1);
          outv = val * cs.x + sgn * p * cs.y;
        }
        if (r < MROWS) {
          const int b = r / 577;
          dst[((size_t)(b * 16 + h) * 577 + s) * 88 + d] = (__bf16)outv;
        }
      }
    }
  }
}

// ---------------- GEMM2: out = ctx @ Wo^T + bo (fp32 out) ----------------
__launch_bounds__(512, 2)
__global__ void gemm_out_bias(const __bf16* __restrict__ A, const __bf16* __restrict__ Bm,
                              const float* __restrict__ bias, float* __restrict__ C) {
  __shared__ __align__(16) __bf16 lds[65536];
  const int wgid = xcd_swizzle(blockIdx.x, 37 * 6);
  const int m0 = (wgid % 37) * 256, n0 = (wgid / 37) * 256;
  f32x4 acc[8][4];
  gemm256_core(A, Bm, m0, n0, MROWS, D_, lds, acc);

  const int tid = threadIdx.x;
  const int w = tid >> 6, l = tid & 63;
  const int wm = w >> 2, wn = w & 3;
#pragma unroll
  for (int n = 0; n < 4; ++n) {
    const int col = n0 + (n >> 1) * 128 + wn * 32 + (n & 1) * 16 + (l & 15);
    if (col >= D_) continue;
    const float bv = bias[col];
#pragma unroll
    for (int m = 0; m < 8; ++m) {
      const int rb = m0 + (m >> 2) * 128 + wm * 64 + (m & 3) * 16 + (l >> 4) * 4;
#pragma unroll
      for (int j = 0; j < 4; ++j) {
        const int r = rb + j;
        if (r < MROWS) C[(size_t)r * D_ + col] = acc[m][n][j] + bv;
      }
    }
  }
}

// ---------------- V transpose: v_bf [bh][577][88] -> Vt_g [bh][88][592] ----------------
__global__ void transpose_v(const __bf16* __restrict__ V, __bf16* __restrict__ Vt_g) {
  __shared__ __bf16 Ls[64 * 104];
  const int bh = blockIdx.x, t = blockIdx.y, s0 = t * 64;
  const int tid = threadIdx.x;
  const __bf16* vp = V + (size_t)bh * 577 * 88;
  for (int i = tid; i < 64 * 11; i += 256) {
    int r = i / 11, off = i % 11;
    int gs = s0 + r; if (gs > 576) gs = 576;
    *(uint4v*)&Ls[r * 104 + off * 8] = *(const uint4v*)(vp + (size_t)gs * 88 + off * 8);
  }
  __syncthreads();
  for (int i = tid; i < 88 * 8; i += 256) {
    int d = i / 8, so = (i % 8) * 8;
    int sc_ = s0 + so;
    if (sc_ < VT_LD) {
      __bf16 tmp[8];
#pragma unroll
      for (int j = 0; j < 8; ++j) tmp[j] = Ls[(so + j) * 104 + d];
      *(uint4v*)&Vt_g[((size_t)bh * 88 + d) * VT_LD + sc_] = *(uint4v*)tmp;
    }
  }
}

// ---------------- flash attention: block = (bh, 128 q-rows), 4 waves x 32 rows ----------------
__launch_bounds__(256, 3)
__global__ void attn_kernel(const __bf16* __restrict__ Q, const __bf16* __restrict__ K,
                            const __bf16* __restrict__ Vt_gp, __bf16* __restrict__ ctx) {
  __shared__ __bf16 lds[26368];
  const int tid = threadIdx.x;
  const int w = tid >> 6, l = tid & 63;
  const int bh = blockIdx.x;
  const int q0 = blockIdx.y * 128;
  const __bf16* qp = Q + (size_t)bh * 577 * 88;
  const __bf16* kp = K + (size_t)bh * 577 * 88;
  const __bf16* vtp = Vt_gp + (size_t)bh * 88 * VT_LD;
  __bf16* Qs = lds;             // [128][96]
  __bf16* Ks = lds + 12288;     // [64][88]
  __bf16* Vt = lds + 17920;     // [96][88]
  __bf16* Pw = lds + w * 2304;  // per-wave P [32][72]

  for (int i = tid; i < 128 * 11; i += 256) {
    int r = i / 11, off = i % 11;
    int gr = q0 + r; if (gr > 576) gr = 576;
    *(uint4v*)&Qs[r * 96 + off * 8] = *(const uint4v*)(qp + (size_t)gr * 88 + off * 8);
  }
  if (tid < 128) { uint4v z = 0; *(uint4v*)&Qs[tid * 96 + 88] = z; }
  __syncthreads();

  bf16x8 qf[2][3];
#pragma unroll
  for (int mg = 0; mg < 2; ++mg)
#pragma unroll
    for (int kk = 0; kk < 3; ++kk)
      qf[mg][kk] = *(const bf16x8*)&Qs[(w * 32 + mg * 16 + (l & 15)) * 96 + kk * 32 + (l >> 4) * 8];

  int preA[7], preB[7];
#pragma unroll
  for (int kch = 0; kch < 7; ++kch) {
    int c = w + 4 * kch;
    int a = 0, b2 = 0;
    if (c < 11) a = c * 512 + l * 8;
    else if (c < 27) { int e = (c - 11) * 512 + l * 8; a = (e / 88) * VT_LD; b2 = e % 88; }
    preA[kch] = a; preB[kch] = b2;
  }

  f32x4 oacc[2][6];
#pragma unroll
  for (int mg = 0; mg < 2; ++mg)
#pragma unroll
    for (int dn = 0; dn < 6; ++dn) oacc[mg][dn] = (f32x4){0.f, 0.f, 0.f, 0.f};
  f32x4 mrun[2], lrun[2];
  mrun[0] = -1e30f; mrun[1] = -1e30f;
  lrun[0] = 0.f; lrun[1] = 0.f;

  for (int t = 0; t < 10; ++t) {
    const int s0 = t * 64;
    if (t) __syncthreads();
#pragma unroll
    for (int kch = 0; kch < 7; ++kch) {
      int c = w + 4 * kch;
      if (c < 11) {
        async16(Ks + c * 512, kp + (size_t)s0 * 88 + preA[kch]);
      } else if (c < 27) {
        int g = s0 + preB[kch]; if (g > 584) g = 584;
        async16(Vt + (c - 11) * 512, vtp + preA[kch] + g);
      }
    }
    __syncthreads();

    f32x4 sc[2][4];
#pragma unroll
    for (int mg = 0; mg < 2; ++mg)
#pragma unroll
      for (int n = 0; n < 4; ++n) sc[mg][n] = (f32x4){0.f, 0.f, 0.f, 0.f};
#pragma unroll
    for (int n = 0; n < 4; ++n) {
#pragma unroll
      for (int kk = 0; kk < 3; ++kk) {
        bf16x8 kf = *(const bf16x8*)&Ks[(n * 16 + (l & 15)) * 88 + kk * 32 + (l >> 4) * 8];
        sc[0][n] = __builtin_amdgcn_mfma_f32_16x16x32_bf16(qf[0][kk], kf, sc[0][n], 0, 0, 0);
        sc[1][n] = __builtin_amdgcn_mfma_f32_16x16x32_bf16(qf[1][kk], kf, sc[1][n], 0, 0, 0);
      }
    }

    f32x4 tmax[2];
    tmax[0] = -1e30f; tmax[1] = -1e30f;
#pragma unroll
    for (int n = 0; n < 4; ++n) {
      const int kc = s0 + n * 16 + (l & 15);
      const bool valid = kc < 577;
#pragma unroll
      for (int mg = 0; mg < 2; ++mg)
#pragma unroll
        for (int j = 0; j < 4; ++j) {
          float v = valid ? sc[mg][n][j] * SCALE : -1e30f;
          sc[mg][n][j] = v;
          tmax[mg][j] = fmaxf(tmax[mg][j], v);
        }
    }
#pragma unroll
    for (int o = 1; o < 16; o <<= 1)
#pragma unroll
      for (int mg = 0; mg < 2; ++mg)
#pragma unroll
        for (int j = 0; j < 4; ++j)
          tmax[mg][j] = fmaxf(tmax[mg][j], __shfl_xor(tmax[mg][j], o));
#pragma unroll
    for (int mg = 0; mg < 2; ++mg)
#pragma unroll
      for (int j = 0; j < 4; ++j) {
        float mo = mrun[mg][j];
        float mn = fmaxf(mo, tmax[mg][j]);
        float sf = __expf(mo - mn);
        mrun[mg][j] = mn;
        lrun[mg][j] *= sf;
#pragma unroll
        for (int dn = 0; dn < 6; ++dn) oacc[mg][dn][j] *= sf;
      }
#pragma unroll
    for (int mg = 0; mg < 2; ++mg)
#pragma unroll
      for (int n = 0; n < 4; ++n)
#pragma unroll
        for (int j = 0; j < 4; ++j) {
          float p = __expf(sc[mg][n][j] - mrun[mg][j]);
          lrun[mg][j] += p;
          Pw[(mg * 16 + (l >> 4) * 4 + j) * 72 + n * 16 + (l & 15)] = (__bf16)p;
        }

#pragma unroll
    for (int ks = 0; ks < 2; ++ks) {
      bf16x8 pa0 = *(const bf16x8*)&Pw[((l & 15)) * 72 + ks * 32 + (l >> 4) * 8];
      bf16x8 pa1 = *(const bf16x8*)&Pw[(16 + (l & 15)) * 72 + ks * 32 + (l >> 4) * 8];
#pragma unroll
      for (int dn = 0; dn < 6; ++dn) {
        bf16x8 vb = *(const bf16x8*)&Vt[(dn * 16 + (l & 15)) * 88 + ks * 32 + (l >> 4) * 8];
        oacc[0][dn] = __builtin_amdgcn_mfma_f32_16x16x32_bf16(pa0, vb, oacc[0][dn], 0, 0, 0);
        oacc[1][dn] = __builtin_amdgcn_mfma_f32_16x16x32_bf16(pa1, vb, oacc[1][dn], 0, 0, 0);
      }
    }
  }

#pragma unroll
  for (int o = 1; o < 16; o <<= 1)
#pragma unroll
    for (int mg = 0; mg < 2; ++mg)
#pragma unroll
      for (int j = 0; j < 4; ++j)
        lrun[mg][j] += __shfl_xor(lrun[mg][j], o);

  const int b = bh >> 4, h = bh & 15;
#pragma unroll
  for (int mg = 0; mg < 2; ++mg) {
    float inv[4];
#pragma unroll
    for (int j = 0; j < 4; ++j) inv[j] = 1.f / lrun[mg][j];
    const int sqb = q0 + w * 32 + mg * 16 + (l >> 4) * 4;
#pragma unroll
    for (int dn = 0; dn < 6; ++dn) {
      const int d = dn * 16 + (l & 15);
      if (d >= 88) continue;
#pragma unroll
      for (int j = 0; j < 4; ++j) {
        const int sq = sqb + j;
        if (sq < 577)
          ctx[((size_t)(b * 577 + sq)) * 1408 + h * 88 + d] = (__bf16)(oacc[mg][dn][j] * inv[j]);
      }
    }
  }
}

extern "C" void kernel_launch(void* const* d_in, const int* in_sizes, int n_in,
                              void* d_out, int out_size, void* d_ws, size_t ws_size,
                              hipStream_t stream) {
  const float* hs    = (const float*)d_in[0];
  const float* freqs = (const float*)d_in[1];
  const float* wqkv  = (const float*)d_in[2];
  const float* bqkv  = (const float*)d_in[3];
  const float* wo    = (const float*)d_in[4];
  const float* bo    = (const float*)d_in[5];
  float* out = (float*)d_out;

  char* ws = (char*)d_ws;
  size_t off = 0;
  auto alloc = [&](size_t bytes) {
    void* p = ws + off;
    off += (bytes + 255) & ~(size_t)255;
    return p;
  };
  __bf16* x_bf    = (__bf16*)alloc((size_t)MROWS * K_ * 2);
  __bf16* ctx_bf  = x_bf;  // aliased: x dead after GEMM1
  __bf16* wqkv_bf = (__bf16*)alloc((size_t)N1 * K_ * 2);
  __bf16* wo_bf   = (__bf16*)alloc((size_t)D_ * K_ * 2);
  __bf16* q_bf    = (__bf16*)alloc((size_t)MROWS * D_ * 2);
  __bf16* k_bf    = (__bf16*)alloc((size_t)MROWS * D_ * 2);
  __bf16* v_bf    = (__bf16*)alloc((size_t)MROWS * D_ * 2);
  __bf16* vt_g    = (__bf16*)d_out;  // V^T scratch in d_out; GEMM2 overwrites later

  cast_bf16_kernel<<<(MROWS * K_ / 4 + 255) / 256, 256, 0, stream>>>(hs, x_bf, MROWS * K_ / 4);
  cast_bf16_kernel<<<(N1 * K_ / 4 + 255) / 256, 256, 0, stream>>>(wqkv, wqkv_bf, N1 * K_ / 4);
  cast_bf16_kernel<<<(D_ * K_ / 4 + 255) / 256, 256, 0, stream>>>(wo, wo_bf, D_ * K_ / 4);

  gemm_qkv_rope<<<37 * 17, 512, 0, stream>>>(x_bf, wqkv_bf, bqkv, freqs, q_bf, k_bf, v_bf);

  transpose_v<<<dim3(256, 10), 256, 0, stream>>>(v_bf, vt_g);

  attn_kernel<<<dim3(256, 5), 256, 0, stream>>>(q_bf, k_bf, vt_g, ctx_bf);

  gemm_out_bias<<<37 * 6, 512, 0, stream>>>(ctx_bf, wo_bf, bo, out);
}

// Round 9
// 416.359 us; speedup vs baseline: 4.4901x; 1.0122x over previous
//
#include <hip/hip_runtime.h>

typedef __attribute__((ext_vector_type(8))) __bf16 bf16x8;
typedef __attribute__((ext_vector_type(4))) float f32x4;
typedef __attribute__((ext_vector_type(4))) unsigned int uint4v;

#define B_ 16
#define S_ 577
#define D_ 1408
#define H_ 16
#define HD_ 88
#define MROWS (B_*S_)   // 9232
#define N1 (3*D_)       // 4224
#define K_ D_           // 1408
#define KSTEPS 44       // 1408/32
#define VT_LD 592
#define SCALE 0.10660035817780521f

static __device__ __forceinline__ void async16(void* lds, const void* g) {
  __builtin_amdgcn_global_load_lds((const __attribute__((address_space(1))) void*)g,
                                   (__attribute__((address_space(3))) void*)lds, 16, 0, 0);
}

// bijective XCD-aware remap (m204): contiguous wgid chunk per XCD
static __device__ __forceinline__ int xcd_swizzle(int orig, int nwg) {
  int xcd = orig & 7, lid = orig >> 3;
  int q = nwg >> 3, r = nwg & 7;
  return (xcd < r ? xcd * (q + 1) : r * (q + 1) + (xcd - r) * q) + lid;
}

// ---------------- cast fp32 -> bf16 (vectorized) ----------------
__global__ void cast_bf16_kernel(const float* __restrict__ src, __bf16* __restrict__ dst, int n4) {
  int i = blockIdx.x * blockDim.x + threadIdx.x;
  if (i >= n4) return;
  const float4 v = ((const float4*)src)[i];
  __bf16* d = dst + (size_t)i * 4;
  d[0] = (__bf16)v.x; d[1] = (__bf16)v.y; d[2] = (__bf16)v.z; d[3] = (__bf16)v.w;
}

// ---------------- GEMM1: qkv = x @ Wqkv^T + b, fused RoPE+split+permute ----------------
// 128x128 tile, BK=32, 2-phase dbuf (R4 core, proven), cheap m-outer epilogue.
__launch_bounds__(256, 2)
__global__ void gemm_qkv_rope(const __bf16* __restrict__ A, const __bf16* __restrict__ Bm,
                              const float* __restrict__ bias, const float* __restrict__ freqs,
                              __bf16* __restrict__ Qb, __bf16* __restrict__ Kb,
                              __bf16* __restrict__ Vb) {
  __shared__ __bf16 As[2][128 * 32];
  __shared__ __bf16 Bs[2][128 * 32];
  const int tid = threadIdx.x;
  const int w = tid >> 6, l = tid & 63;
  const int wgid = xcd_swizzle(blockIdx.x, 33 * 73);
  const int m0 = (wgid % 73) * 128, n0 = (wgid / 73) * 128;
  const int wr = w & 1, wc = w >> 1;
  const int M = MROWS, K = K_;

  f32x4 acc[4][4];
#pragma unroll
  for (int m = 0; m < 4; ++m)
#pragma unroll
    for (int n = 0; n < 4; ++n) acc[m][n] = (f32x4){0.f, 0.f, 0.f, 0.f};

  int arow0 = m0 + w * 32 + (l >> 2);      if (arow0 >= M) arow0 = M - 1;
  int arow1 = m0 + w * 32 + 16 + (l >> 2); if (arow1 >= M) arow1 = M - 1;
  const __bf16* ag0 = A + (size_t)arow0 * K + (l & 3) * 8;
  const __bf16* ag1 = A + (size_t)arow1 * K + (l & 3) * 8;
  const __bf16* bg0 = Bm + (size_t)(n0 + w * 32 + (l >> 2)) * K + (l & 3) * 8;
  const __bf16* bg1 = Bm + (size_t)(n0 + w * 32 + 16 + (l >> 2)) * K + (l & 3) * 8;

  auto stage = [&](int buf, int k0) {
    async16(&As[buf][(w * 32) * 32],      ag0 + k0);
    async16(&As[buf][(w * 32 + 16) * 32], ag1 + k0);
    async16(&Bs[buf][(w * 32) * 32],      bg0 + k0);
    async16(&Bs[buf][(w * 32 + 16) * 32], bg1 + k0);
  };

  stage(0, 0);
  __syncthreads();
  for (int t = 0; t < KSTEPS; ++t) {
    const int cur = t & 1;
    if (t < KSTEPS - 1) stage(cur ^ 1, (t + 1) * 32);
    bf16x8 a[4], b[4];
#pragma unroll
    for (int m = 0; m < 4; ++m)
      a[m] = *(const bf16x8*)&As[cur][(wr * 64 + m * 16 + (l & 15)) * 32 + (l >> 4) * 8];
#pragma unroll
    for (int n = 0; n < 4; ++n)
      b[n] = *(const bf16x8*)&Bs[cur][(wc * 64 + n * 16 + (l & 15)) * 32 + (l >> 4) * 8];
#pragma unroll
    for (int m = 0; m < 4; ++m)
#pragma unroll
      for (int n = 0; n < 4; ++n)
        acc[m][n] = __builtin_amdgcn_mfma_f32_16x16x32_bf16(a[m], b[n], acc[m][n], 0, 0, 0);
    __syncthreads();
  }

  // ---- cheap epilogue: per-col constants hoisted, m-outer (s,b,rows computed once) ----
  const int sect = n0 / 1408;  // 0=q 1=k 2=v, uniform per block
  __bf16* dst = (sect == 0) ? Qb : (sect == 1 ? Kb : Vb);
  int hN[4], dN[4], i2N[4];
  float bvN[4], sgnN[4];
#pragma unroll
  for (int n = 0; n < 4; ++n) {
    const int col = n0 + wc * 64 + n * 16 + (l & 15);
    const int cin = col - sect * 1408;
    hN[n] = cin / 88; dN[n] = cin - hN[n] * 88;
    bvN[n] = bias[col];
    i2N[n] = dN[n] & ~1;
    sgnN[n] = (dN[n] & 1) ? 1.f : -1.f;
  }
#pragma unroll
  for (int m = 0; m < 4; ++m) {
    const int rbase = m0 + wr * 64 + m * 16 + (l >> 4) * 4;
#pragma unroll
    for (int j = 0; j < 4; ++j) {
      const int r = rbase + j;
      const int s = r % 577;            // safe even for clamped OOB rows
      const int b = r / 577;
      const bool ok = r < MROWS;
      const float* frow = freqs + s * 88;
      __bf16* drow = dst + ((size_t)b * 16 * 577 + s) * 88;
#pragma unroll
      for (int n = 0; n < 4; ++n) {
        float val = acc[m][n][j] + bvN[n];
        float outv = val;
        if (sect < 2) {
          const float2 cs = *(const float2*)&frow[i2N[n]];
          const float p = __shfl_xor(val, 1);   // all lanes execute
          outv = val * cs.x + sgnN[n] * p * cs.y;
        }
        if (ok) drow[(size_t)hN[n] * 50776 + dN[n]] = (__bf16)outv;  // 50776 = 577*88
      }
    }
  }
}

// ---------------- GEMM2: out = ctx @ Wo^T + bo (fp32 out), same 2-phase loop ----------------
__launch_bounds__(256, 2)
__global__ void gemm_out_bias(const __bf16* __restrict__ A, const __bf16* __restrict__ Bm,
                              const float* __restrict__ bias, float* __restrict__ C) {
  __shared__ __bf16 As[2][128 * 32];
  __shared__ __bf16 Bs[2][128 * 32];
  const int tid = threadIdx.x;
  const int w = tid >> 6, l = tid & 63;
  const int wgid = xcd_swizzle(blockIdx.x, 11 * 73);
  const int m0 = (wgid % 73) * 128, n0 = (wgid / 73) * 128;
  const int wr = w & 1, wc = w >> 1;
  const int M = MROWS, N = D_, K = K_;

  f32x4 acc[4][4];
#pragma unroll
  for (int m = 0; m < 4; ++m)
#pragma unroll
    for (int n = 0; n < 4; ++n) acc[m][n] = (f32x4){0.f, 0.f, 0.f, 0.f};

  int arow0 = m0 + w * 32 + (l >> 2);      if (arow0 >= M) arow0 = M - 1;
  int arow1 = m0 + w * 32 + 16 + (l >> 2); if (arow1 >= M) arow1 = M - 1;
  const __bf16* ag0 = A + (size_t)arow0 * K + (l & 3) * 8;
  const __bf16* ag1 = A + (size_t)arow1 * K + (l & 3) * 8;
  const __bf16* bg0 = Bm + (size_t)(n0 + w * 32 + (l >> 2)) * K + (l & 3) * 8;
  const __bf16* bg1 = Bm + (size_t)(n0 + w * 32 + 16 + (l >> 2)) * K + (l & 3) * 8;

  auto stage = [&](int buf, int k0) {
    async16(&As[buf][(w * 32) * 32],      ag0 + k0);
    async16(&As[buf][(w * 32 + 16) * 32], ag1 + k0);
    async16(&Bs[buf][(w * 32) * 32],      bg0 + k0);
    async16(&Bs[buf][(w * 32 + 16) * 32], bg1 + k0);
  };

  stage(0, 0);
  __syncthreads();
  for (int t = 0; t < KSTEPS; ++t) {
    const int cur = t & 1;
    if (t < KSTEPS - 1) stage(cur ^ 1, (t + 1) * 32);
    bf16x8 a[4], b[4];
#pragma unroll
    for (int m = 0; m < 4; ++m)
      a[m] = *(const bf16x8*)&As[cur][(wr * 64 + m * 16 + (l & 15)) * 32 + (l >> 4) * 8];
#pragma unroll
    for (int n = 0; n < 4; ++n)
      b[n] = *(const bf16x8*)&Bs[cur][(wc * 64 + n * 16 + (l & 15)) * 32 + (l >> 4) * 8];
#pragma unroll
    for (int m = 0; m < 4; ++m)
#pragma unroll
      for (int n = 0; n < 4; ++n)
        acc[m][n] = __builtin_amdgcn_mfma_f32_16x16x32_bf16(a[m], b[n], acc[m][n], 0, 0, 0);
    __syncthreads();
  }

#pragma unroll
  for (int n = 0; n < 4; ++n) {
    int col = n0 + wc * 64 + n * 16 + (l & 15);
    float bv = bias[col];
#pragma unroll
    for (int m = 0; m < 4; ++m) {
      int rbase = m0 + wr * 64 + m * 16 + (l >> 4) * 4;
#pragma unroll
      for (int j = 0; j < 4; ++j) {
        int r = rbase + j;
        if (r < MROWS) C[(size_t)r * N + col] = acc[m][n][j] + bv;
      }
    }
  }
}

// ---------------- V transpose: v_bf [bh][577][88] -> Vt_g [bh][88][592] ----------------
__global__ void transpose_v(const __bf16* __restrict__ V, __bf16* __restrict__ Vt_g) {
  __shared__ __bf16 Ls[64 * 104];
  const int bh = blockIdx.x, t = blockIdx.y, s0 = t * 64;
  const int tid = threadIdx.x;
  const __bf16* vp = V + (size_t)bh * 577 * 88;
  for (int i = tid; i < 64 * 11; i += 256) {
    int r = i / 11, off = i % 11;
    int gs = s0 + r; if (gs > 576) gs = 576;
    *(uint4v*)&Ls[r * 104 + off * 8] = *(const uint4v*)(vp + (size_t)gs * 88 + off * 8);
  }
  __syncthreads();
  for (int i = tid; i < 88 * 8; i += 256) {
    int d = i / 8, so = (i % 8) * 8;
    int sc_ = s0 + so;
    if (sc_ < VT_LD) {
      __bf16 tmp[8];
#pragma unroll
      for (int j = 0; j < 8; ++j) tmp[j] = Ls[(so + j) * 104 + d];
      *(uint4v*)&Vt_g[((size_t)bh * 88 + d) * VT_LD + sc_] = *(uint4v*)tmp;
    }
  }
}

// ---------------- flash attention: block = (bh, 128 q-rows), 4 waves x 32 rows ----------------
__launch_bounds__(256, 3)
__global__ void attn_kernel(const __bf16* __restrict__ Q, const __bf16* __restrict__ K,
                            const __bf16* __restrict__ Vt_gp, __bf16* __restrict__ ctx) {
  __shared__ __bf16 lds[26368];
  const int tid = threadIdx.x;
  const int w = tid >> 6, l = tid & 63;
  const int bh = blockIdx.x;
  const int q0 = blockIdx.y * 128;
  const __bf16* qp = Q + (size_t)bh * 577 * 88;
  const __bf16* kp = K + (size_t)bh * 577 * 88;
  const __bf16* vtp = Vt_gp + (size_t)bh * 88 * VT_LD;
  __bf16* Qs = lds;             // [128][96]
  __bf16* Ks = lds + 12288;     // [64][88]
  __bf16* Vt = lds + 17920;     // [96][88]
  __bf16* Pw = lds + w * 2304;  // per-wave P [32][72]

  for (int i = tid; i < 128 * 11; i += 256) {
    int r = i / 11, off = i % 11;
    int gr = q0 + r; if (gr > 576) gr = 576;
    *(uint4v*)&Qs[r * 96 + off * 8] = *(const uint4v*)(qp + (size_t)gr * 88 + off * 8);
  }
  if (tid < 128) { uint4v z = 0; *(uint4v*)&Qs[tid * 96 + 88] = z; }
  __syncthreads();

  bf16x8 qf[2][3];
#pragma unroll
  for (int mg = 0; mg < 2; ++mg)
#pragma unroll
    for (int kk = 0; kk < 3; ++kk)
      qf[mg][kk] = *(const bf16x8*)&Qs[(w * 32 + mg * 16 + (l & 15)) * 96 + kk * 32 + (l >> 4) * 8];

  int preA[7], preB[7];
#pragma unroll
  for (int kch = 0; kch < 7; ++kch) {
    int c = w + 4 * kch;
    int a = 0, b2 = 0;
    if (c < 11) a = c * 512 + l * 8;
    else if (c < 27) { int e = (c - 11) * 512 + l * 8; a = (e / 88) * VT_LD; b2 = e % 88; }
    preA[kch] = a; preB[kch] = b2;
  }

  f32x4 oacc[2][6];
#pragma unroll
  for (int mg = 0; mg < 2; ++mg)
#pragma unroll
    for (int dn = 0; dn < 6; ++dn) oacc[mg][dn] = (f32x4){0.f, 0.f, 0.f, 0.f};
  f32x4 mrun[2], lrun[2];
  mrun[0] = -1e30f; mrun[1] = -1e30f;
  lrun[0] = 0.f; lrun[1] = 0.f;

  for (int t = 0; t < 10; ++t) {
    const int s0 = t * 64;
    if (t) __syncthreads();
#pragma unroll
    for (int kch = 0; kch < 7; ++kch) {
      int c = w + 4 * kch;
      if (c < 11) {
        async16(Ks + c * 512, kp + (size_t)s0 * 88 + preA[kch]);
      } else if (c < 27) {
        int g = s0 + preB[kch]; if (g > 584) g = 584;
        async16(Vt + (c - 11) * 512, vtp + preA[kch] + g);
      }
    }
    __syncthreads();

    f32x4 sc[2][4];
#pragma unroll
    for (int mg = 0; mg < 2; ++mg)
#pragma unroll
      for (int n = 0; n < 4; ++n) sc[mg][n] = (f32x4){0.f, 0.f, 0.f, 0.f};
#pragma unroll
    for (int n = 0; n < 4; ++n) {
#pragma unroll
      for (int kk = 0; kk < 3; ++kk) {
        bf16x8 kf = *(const bf16x8*)&Ks[(n * 16 + (l & 15)) * 88 + kk * 32 + (l >> 4) * 8];
        sc[0][n] = __builtin_amdgcn_mfma_f32_16x16x32_bf16(qf[0][kk], kf, sc[0][n], 0, 0, 0);
        sc[1][n] = __builtin_amdgcn_mfma_f32_16x16x32_bf16(qf[1][kk], kf, sc[1][n], 0, 0, 0);
      }
    }

    f32x4 tmax[2];
    tmax[0] = -1e30f; tmax[1] = -1e30f;
#pragma unroll
    for (int n = 0; n < 4; ++n) {
      const int kc = s0 + n * 16 + (l & 15);
      const bool valid = kc < 577;
#pragma unroll
      for (int mg = 0; mg < 2; ++mg)
#pragma unroll
        for (int j = 0; j < 4; ++j) {
          float v = valid ? sc[mg][n][j] * SCALE : -1e30f;
          sc[mg][n][j] = v;
          tmax[mg][j] = fmaxf(tmax[mg][j], v);
        }
    }
#pragma unroll
    for (int o = 1; o < 16; o <<= 1)
#pragma unroll
      for (int mg = 0; mg < 2; ++mg)
#pragma unroll
        for (int j = 0; j < 4; ++j)
          tmax[mg][j] = fmaxf(tmax[mg][j], __shfl_xor(tmax[mg][j], o));
#pragma unroll
    for (int mg = 0; mg < 2; ++mg)
#pragma unroll
      for (int j = 0; j < 4; ++j) {
        float mo = mrun[mg][j];
        float mn = fmaxf(mo, tmax[mg][j]);
        float sf = __expf(mo - mn);
        mrun[mg][j] = mn;
        lrun[mg][j] *= sf;
#pragma unroll
        for (int dn = 0; dn < 6; ++dn) oacc[mg][dn][j] *= sf;
      }
#pragma unroll
    for (int mg = 0; mg < 2; ++mg)
#pragma unroll
      for (int n = 0; n < 4; ++n)
#pragma unroll
        for (int j = 0; j < 4; ++j) {
          float p = __expf(sc[mg][n][j] - mrun[mg][j]);
          lrun[mg][j] += p;
          Pw[(mg * 16 + (l >> 4) * 4 + j) * 72 + n * 16 + (l & 15)] = (__bf16)p;
        }

#pragma unroll
    for (int ks = 0; ks < 2; ++ks) {
      bf16x8 pa0 = *(const bf16x8*)&Pw[((l & 15)) * 72 + ks * 32 + (l >> 4) * 8];
      bf16x8 pa1 = *(const bf16x8*)&Pw[(16 + (l & 15)) * 72 + ks * 32 + (l >> 4) * 8];
#pragma unroll
      for (int dn = 0; dn < 6; ++dn) {
        bf16x8 vb = *(const bf16x8*)&Vt[(dn * 16 + (l & 15)) * 88 + ks * 32 + (l >> 4) * 8];
        oacc[0][dn] = __builtin_amdgcn_mfma_f32_16x16x32_bf16(pa0, vb, oacc[0][dn], 0, 0, 0);
        oacc[1][dn] = __builtin_amdgcn_mfma_f32_16x16x32_bf16(pa1, vb, oacc[1][dn], 0, 0, 0);
      }
    }
  }

#pragma unroll
  for (int o = 1; o < 16; o <<= 1)
#pragma unroll
    for (int mg = 0; mg < 2; ++mg)
#pragma unroll
      for (int j = 0; j < 4; ++j)
        lrun[mg][j] += __shfl_xor(lrun[mg][j], o);

  const int b = bh >> 4, h = bh & 15;
#pragma unroll
  for (int mg = 0; mg < 2; ++mg) {
    float inv[4];
#pragma unroll
    for (int j = 0; j < 4; ++j) inv[j] = 1.f / lrun[mg][j];
    const int sqb = q0 + w * 32 + mg * 16 + (l >> 4) * 4;
#pragma unroll
    for (int dn = 0; dn < 6; ++dn) {
      const int d = dn * 16 + (l & 15);
      if (d >= 88) continue;
#pragma unroll
      for (int j = 0; j < 4; ++j) {
        const int sq = sqb + j;
        if (sq < 577)
          ctx[((size_t)(b * 577 + sq)) * 1408 + h * 88 + d] = (__bf16)(oacc[mg][dn][j] * inv[j]);
      }
    }
  }
}

extern "C" void kernel_launch(void* const* d_in, const int* in_sizes, int n_in,
                              void* d_out, int out_size, void* d_ws, size_t ws_size,
                              hipStream_t stream) {
  const float* hs    = (const float*)d_in[0];
  const float* freqs = (const float*)d_in[1];
  const float* wqkv  = (const float*)d_in[2];
  const float* bqkv  = (const float*)d_in[3];
  const float* wo    = (const float*)d_in[4];
  const float* bo    = (const float*)d_in[5];
  float* out = (float*)d_out;

  char* ws = (char*)d_ws;
  size_t off = 0;
  auto alloc = [&](size_t bytes) {
    void* p = ws + off;
    off += (bytes + 255) & ~(size_t)255;
    return p;
  };
  __bf16* x_bf    = (__bf16*)alloc((size_t)MROWS * K_ * 2);
  __bf16* ctx_bf  = x_bf;  // aliased: x dead after GEMM1
  __bf16* wqkv_bf = (__bf16*)alloc((size_t)N1 * K_ * 2);
  __bf16* wo_bf   = (__bf16*)alloc((size_t)D_ * K_ * 2);
  __bf16* q_bf    = (__bf16*)alloc((size_t)MROWS * D_ * 2);
  __bf16* k_bf    = (__bf16*)alloc((size_t)MROWS * D_ * 2);
  __bf16* v_bf    = (__bf16*)alloc((size_t)MROWS * D_ * 2);
  __bf16* vt_g    = (__bf16*)d_out;  // V^T scratch in d_out; GEMM2 overwrites later

  cast_bf16_kernel<<<(MROWS * K_ / 4 + 255) / 256, 256, 0, stream>>>(hs, x_bf, MROWS * K_ / 4);
  cast_bf16_kernel<<<(N1 * K_ / 4 + 255) / 256, 256, 0, stream>>>(wqkv, wqkv_bf, N1 * K_ / 4);
  cast_bf16_kernel<<<(D_ * K_ / 4 + 255) / 256, 256, 0, stream>>>(wo, wo_bf, D_ * K_ / 4);

  gemm_qkv_rope<<<33 * 73, 256, 0, stream>>>(x_bf, wqkv_bf, bqkv, freqs, q_bf, k_bf, v_bf);

  transpose_v<<<dim3(256, 10), 256, 0, stream>>>(v_bf, vt_g);

  attn_kernel<<<dim3(256, 5), 256, 0, stream>>>(q_bf, k_bf, vt_g, ctx_bf);

  gemm_out_bias<<<11 * 73, 256, 0, stream>>>(ctx_bf, wo_bf, bo, out);
}

// Round 10
// 393.051 us; speedup vs baseline: 4.7564x; 1.0593x over previous
//
#include <hip/hip_runtime.h>

typedef __attribute__((ext_vector_type(8))) __bf16 bf16x8;
typedef __attribute__((ext_vector_type(4))) float f32x4;
typedef __attribute__((ext_vector_type(4))) unsigned int uint4v;

#define B_ 16
#define S_ 577
#define D_ 1408
#define H_ 16
#define HD_ 88
#define MROWS (B_*S_)   // 9232
#define N1 (3*D_)       // 4224
#define K_ D_           // 1408
#define KSTEPS 44       // 1408/32
#define VT_LD 592
#define SCALE 0.10660035817780521f

static __device__ __forceinline__ void async16(void* lds, const void* g) {
  __builtin_amdgcn_global_load_lds((const __attribute__((address_space(1))) void*)g,
                                   (__attribute__((address_space(3))) void*)lds, 16, 0, 0);
}

// bijective XCD-aware remap (m204): contiguous wgid chunk per XCD
static __device__ __forceinline__ int xcd_swizzle(int orig, int nwg) {
  int xcd = orig & 7, lid = orig >> 3;
  int q = nwg >> 3, r = nwg & 7;
  return (xcd < r ? xcd * (q + 1) : r * (q + 1) + (xcd - r) * q) + lid;
}

// ---------------- cast fp32 -> bf16 (vectorized) ----------------
__global__ void cast_bf16_kernel(const float* __restrict__ src, __bf16* __restrict__ dst, int n4) {
  int i = blockIdx.x * blockDim.x + threadIdx.x;
  if (i >= n4) return;
  const float4 v = ((const float4*)src)[i];
  __bf16* d = dst + (size_t)i * 4;
  d[0] = (__bf16)v.x; d[1] = (__bf16)v.y; d[2] = (__bf16)v.z; d[3] = (__bf16)v.w;
}

// ---------------- GEMM1: qkv = x @ Wqkv^T + b, fused RoPE+split+permute ----------------
// 128x128 tile, BK=32, 2-phase dbuf. L2-band tile order: bands of 4 M-tiles sweep
// all 33 N-cols (A-band 1.4MB stays L2-resident; B streams, L3-resident).
__launch_bounds__(256, 2)
__global__ void gemm_qkv_rope(const __bf16* __restrict__ A, const __bf16* __restrict__ Bm,
                              const float* __restrict__ bias, const float* __restrict__ freqs,
                              __bf16* __restrict__ Qb, __bf16* __restrict__ Kb,
                              __bf16* __restrict__ Vb) {
  __shared__ __bf16 As[2][128 * 32];
  __shared__ __bf16 Bs[2][128 * 32];
  const int tid = threadIdx.x;
  const int w = tid >> 6, l = tid & 63;
  const int wgid = xcd_swizzle(blockIdx.x, 33 * 73);
  int mt, nt;
  if (wgid < 2376) { int bnd = wgid / 132, r = wgid % 132; nt = r >> 2; mt = bnd * 4 + (r & 3); }
  else             { nt = wgid - 2376; mt = 72; }
  const int m0 = mt * 128, n0 = nt * 128;
  const int wr = w & 1, wc = w >> 1;
  const int M = MROWS, K = K_;

  f32x4 acc[4][4];
#pragma unroll
  for (int m = 0; m < 4; ++m)
#pragma unroll
    for (int n = 0; n < 4; ++n) acc[m][n] = (f32x4){0.f, 0.f, 0.f, 0.f};

  int arow0 = m0 + w * 32 + (l >> 2);      if (arow0 >= M) arow0 = M - 1;
  int arow1 = m0 + w * 32 + 16 + (l >> 2); if (arow1 >= M) arow1 = M - 1;
  const __bf16* ag0 = A + (size_t)arow0 * K + (l & 3) * 8;
  const __bf16* ag1 = A + (size_t)arow1 * K + (l & 3) * 8;
  const __bf16* bg0 = Bm + (size_t)(n0 + w * 32 + (l >> 2)) * K + (l & 3) * 8;
  const __bf16* bg1 = Bm + (size_t)(n0 + w * 32 + 16 + (l >> 2)) * K + (l & 3) * 8;

  auto stage = [&](int buf, int k0) {
    async16(&As[buf][(w * 32) * 32],      ag0 + k0);
    async16(&As[buf][(w * 32 + 16) * 32], ag1 + k0);
    async16(&Bs[buf][(w * 32) * 32],      bg0 + k0);
    async16(&Bs[buf][(w * 32 + 16) * 32], bg1 + k0);
  };

  stage(0, 0);
  __syncthreads();
  for (int t = 0; t < KSTEPS; ++t) {
    const int cur = t & 1;
    if (t < KSTEPS - 1) stage(cur ^ 1, (t + 1) * 32);
    bf16x8 a[4], b[4];
#pragma unroll
    for (int m = 0; m < 4; ++m)
      a[m] = *(const bf16x8*)&As[cur][(wr * 64 + m * 16 + (l & 15)) * 32 + (l >> 4) * 8];
#pragma unroll
    for (int n = 0; n < 4; ++n)
      b[n] = *(const bf16x8*)&Bs[cur][(wc * 64 + n * 16 + (l & 15)) * 32 + (l >> 4) * 8];
#pragma unroll
    for (int m = 0; m < 4; ++m)
#pragma unroll
      for (int n = 0; n < 4; ++n)
        acc[m][n] = __builtin_amdgcn_mfma_f32_16x16x32_bf16(a[m], b[n], acc[m][n], 0, 0, 0);
    __syncthreads();
  }

  // ---- cheap epilogue: per-col constants hoisted, m-outer ----
  const int sect = n0 / 1408;  // 0=q 1=k 2=v, uniform per block
  __bf16* dst = (sect == 0) ? Qb : (sect == 1 ? Kb : Vb);
  int hN[4], dN[4], i2N[4];
  float bvN[4], sgnN[4];
#pragma unroll
  for (int n = 0; n < 4; ++n) {
    const int col = n0 + wc * 64 + n * 16 + (l & 15);
    const int cin = col - sect * 1408;
    hN[n] = cin / 88; dN[n] = cin - hN[n] * 88;
    bvN[n] = bias[col];
    i2N[n] = dN[n] & ~1;
    sgnN[n] = (dN[n] & 1) ? 1.f : -1.f;
  }
#pragma unroll
  for (int m = 0; m < 4; ++m) {
    const int rbase = m0 + wr * 64 + m * 16 + (l >> 4) * 4;
#pragma unroll
    for (int j = 0; j < 4; ++j) {
      const int r = rbase + j;
      const int s = r % 577;
      const int b = r / 577;
      const bool ok = r < MROWS;
      const float* frow = freqs + s * 88;
      __bf16* drow = dst + ((size_t)b * 16 * 577 + s) * 88;
#pragma unroll
      for (int n = 0; n < 4; ++n) {
        float val = acc[m][n][j] + bvN[n];
        float outv = val;
        if (sect < 2) {
          const float2 cs = *(const float2*)&frow[i2N[n]];
          const float p = __shfl_xor(val, 1);   // all lanes execute
          outv = val * cs.x + sgnN[n] * p * cs.y;
        }
        if (ok) drow[(size_t)hN[n] * 50776 + dN[n]] = (__bf16)outv;  // 50776 = 577*88
      }
    }
  }
}

// ---------------- GEMM2: out = ctx @ Wo^T + bo (fp32 out), same 2-phase loop ----------------
__launch_bounds__(256, 2)
__global__ void gemm_out_bias(const __bf16* __restrict__ A, const __bf16* __restrict__ Bm,
                              const float* __restrict__ bias, float* __restrict__ C) {
  __shared__ __bf16 As[2][128 * 32];
  __shared__ __bf16 Bs[2][128 * 32];
  const int tid = threadIdx.x;
  const int w = tid >> 6, l = tid & 63;
  const int wgid = xcd_swizzle(blockIdx.x, 11 * 73);
  int mt, nt;
  if (wgid < 792) { int bnd = wgid / 44, r = wgid % 44; nt = r >> 2; mt = bnd * 4 + (r & 3); }
  else            { nt = wgid - 792; mt = 72; }
  const int m0 = mt * 128, n0 = nt * 128;
  const int wr = w & 1, wc = w >> 1;
  const int M = MROWS, N = D_, K = K_;

  f32x4 acc[4][4];
#pragma unroll
  for (int m = 0; m < 4; ++m)
#pragma unroll
    for (int n = 0; n < 4; ++n) acc[m][n] = (f32x4){0.f, 0.f, 0.f, 0.f};

  int arow0 = m0 + w * 32 + (l >> 2);      if (arow0 >= M) arow0 = M - 1;
  int arow1 = m0 + w * 32 + 16 + (l >> 2); if (arow1 >= M) arow1 = M - 1;
  const __bf16* ag0 = A + (size_t)arow0 * K + (l & 3) * 8;
  const __bf16* ag1 = A + (size_t)arow1 * K + (l & 3) * 8;
  const __bf16* bg0 = Bm + (size_t)(n0 + w * 32 + (l >> 2)) * K + (l & 3) * 8;
  const __bf16* bg1 = Bm + (size_t)(n0 + w * 32 + 16 + (l >> 2)) * K + (l & 3) * 8;

  auto stage = [&](int buf, int k0) {
    async16(&As[buf][(w * 32) * 32],      ag0 + k0);
    async16(&As[buf][(w * 32 + 16) * 32], ag1 + k0);
    async16(&Bs[buf][(w * 32) * 32],      bg0 + k0);
    async16(&Bs[buf][(w * 32 + 16) * 32], bg1 + k0);
  };

  stage(0, 0);
  __syncthreads();
  for (int t = 0; t < KSTEPS; ++t) {
    const int cur = t & 1;
    if (t < KSTEPS - 1) stage(cur ^ 1, (t + 1) * 32);
    bf16x8 a[4], b[4];
#pragma unroll
    for (int m = 0; m < 4; ++m)
      a[m] = *(const bf16x8*)&As[cur][(wr * 64 + m * 16 + (l & 15)) * 32 + (l >> 4) * 8];
#pragma unroll
    for (int n = 0; n < 4; ++n)
      b[n] = *(const bf16x8*)&Bs[cur][(wc * 64 + n * 16 + (l & 15)) * 32 + (l >> 4) * 8];
#pragma unroll
    for (int m = 0; m < 4; ++m)
#pragma unroll
      for (int n = 0; n < 4; ++n)
        acc[m][n] = __builtin_amdgcn_mfma_f32_16x16x32_bf16(a[m], b[n], acc[m][n], 0, 0, 0);
    __syncthreads();
  }

#pragma unroll
  for (int n = 0; n < 4; ++n) {
    int col = n0 + wc * 64 + n * 16 + (l & 15);
    float bv = bias[col];
#pragma unroll
    for (int m = 0; m < 4; ++m) {
      int rbase = m0 + wr * 64 + m * 16 + (l >> 4) * 4;
#pragma unroll
      for (int j = 0; j < 4; ++j) {
        int r = rbase + j;
        if (r < MROWS) C[(size_t)r * N + col] = acc[m][n][j] + bv;
      }
    }
  }
}

// ---------------- V transpose: v_bf [bh][577][88] -> Vt_g [bh][88][592] ----------------
__global__ void transpose_v(const __bf16* __restrict__ V, __bf16* __restrict__ Vt_g) {
  __shared__ __bf16 Ls[64 * 104];
  const int bh = blockIdx.x, t = blockIdx.y, s0 = t * 64;
  const int tid = threadIdx.x;
  const __bf16* vp = V + (size_t)bh * 577 * 88;
  for (int i = tid; i < 64 * 11; i += 256) {
    int r = i / 11, off = i % 11;
    int gs = s0 + r; if (gs > 576) gs = 576;
    *(uint4v*)&Ls[r * 104 + off * 8] = *(const uint4v*)(vp + (size_t)gs * 88 + off * 8);
  }
  __syncthreads();
  for (int i = tid; i < 88 * 8; i += 256) {
    int d = i / 8, so = (i % 8) * 8;
    int sc_ = s0 + so;
    if (sc_ < VT_LD) {
      __bf16 tmp[8];
#pragma unroll
      for (int j = 0; j < 8; ++j) tmp[j] = Ls[(so + j) * 104 + d];
      *(uint4v*)&Vt_g[((size_t)bh * 88 + d) * VT_LD + sc_] = *(uint4v*)tmp;
    }
  }
}

// ---------------- flash attention: block = (bh, 128 q-rows), 4 waves x 32 rows ----------------
__launch_bounds__(256, 3)
__global__ void attn_kernel(const __bf16* __restrict__ Q, const __bf16* __restrict__ K,
                            const __bf16* __restrict__ Vt_gp, __bf16* __restrict__ ctx) {
  __shared__ __bf16 lds[26368];
  const int tid = threadIdx.x;
  const int w = tid >> 6, l = tid & 63;
  const int bh = blockIdx.x;
  const int q0 = blockIdx.y * 128;
  const __bf16* qp = Q + (size_t)bh * 577 * 88;
  const __bf16* kp = K + (size_t)bh * 577 * 88;
  const __bf16* vtp = Vt_gp + (size_t)bh * 88 * VT_LD;
  __bf16* Qs = lds;             // [128][96]
  __bf16* Ks = lds + 12288;     // [64][88]
  __bf16* Vt = lds + 17920;     // [96][88]
  __bf16* Pw = lds + w * 2304;  // per-wave P [32][72]

  for (int i = tid; i < 128 * 11; i += 256) {
    int r = i / 11, off = i % 11;
    int gr = q0 + r; if (gr > 576) gr = 576;
    *(uint4v*)&Qs[r * 96 + off * 8] = *(const uint4v*)(qp + (size_t)gr * 88 + off * 8);
  }
  if (tid < 128) { uint4v z = 0; *(uint4v*)&Qs[tid * 96 + 88] = z; }
  __syncthreads();

  bf16x8 qf[2][3];
#pragma unroll
  for (int mg = 0; mg < 2; ++mg)
#pragma unroll
    for (int kk = 0; kk < 3; ++kk)
      qf[mg][kk] = *(const bf16x8*)&Qs[(w * 32 + mg * 16 + (l & 15)) * 96 + kk * 32 + (l >> 4) * 8];

  int preA[7], preB[7];
#pragma unroll
  for (int kch = 0; kch < 7; ++kch) {
    int c = w + 4 * kch;
    int a = 0, b2 = 0;
    if (c < 11) a = c * 512 + l * 8;
    else if (c < 27) { int e = (c - 11) * 512 + l * 8; a = (e / 88) * VT_LD; b2 = e % 88; }
    preA[kch] = a; preB[kch] = b2;
  }

  f32x4 oacc[2][6];
#pragma unroll
  for (int mg = 0; mg < 2; ++mg)
#pragma unroll
    for (int dn = 0; dn < 6; ++dn) oacc[mg][dn] = (f32x4){0.f, 0.f, 0.f, 0.f};
  f32x4 mrun[2], lrun[2];
  mrun[0] = -1e30f; mrun[1] = -1e30f;
  lrun[0] = 0.f; lrun[1] = 0.f;

  for (int t = 0; t < 10; ++t) {
    const int s0 = t * 64;
    if (t) __syncthreads();
#pragma unroll
    for (int kch = 0; kch < 7; ++kch) {
      int c = w + 4 * kch;
      if (c < 11) {
        async16(Ks + c * 512, kp + (size_t)s0 * 88 + preA[kch]);
      } else if (c < 27) {
        int g = s0 + preB[kch]; if (g > 584) g = 584;
        async16(Vt + (c - 11) * 512, vtp + preA[kch] + g);
      }
    }
    __syncthreads();

    f32x4 sc[2][4];
#pragma unroll
    for (int mg = 0; mg < 2; ++mg)
#pragma unroll
      for (int n = 0; n < 4; ++n) sc[mg][n] = (f32x4){0.f, 0.f, 0.f, 0.f};
#pragma unroll
    for (int n = 0; n < 4; ++n) {
#pragma unroll
      for (int kk = 0; kk < 3; ++kk) {
        bf16x8 kf = *(const bf16x8*)&Ks[(n * 16 + (l & 15)) * 88 + kk * 32 + (l >> 4) * 8];
        sc[0][n] = __builtin_amdgcn_mfma_f32_16x16x32_bf16(qf[0][kk], kf, sc[0][n], 0, 0, 0);
        sc[1][n] = __builtin_amdgcn_mfma_f32_16x16x32_bf16(qf[1][kk], kf, sc[1][n], 0, 0, 0);
      }
    }

    f32x4 tmax[2];
    tmax[0] = -1e30f; tmax[1] = -1e30f;
#pragma unroll
    for (int n = 0; n < 4; ++n) {
      const int kc = s0 + n * 16 + (l & 15);
      const bool valid = kc < 577;
#pragma unroll
      for (int mg = 0; mg < 2; ++mg)
#pragma unroll
        for (int j = 0; j < 4; ++j) {
          float v = valid ? sc[mg][n][j] * SCALE : -1e30f;
          sc[mg][n][j] = v;
          tmax[mg][j] = fmaxf(tmax[mg][j], v);
        }
    }
#pragma unroll
    for (int o = 1; o < 16; o <<= 1)
#pragma unroll
      for (int mg = 0; mg < 2; ++mg)
#pragma unroll
        for (int j = 0; j < 4; ++j)
          tmax[mg][j] = fmaxf(tmax[mg][j], __shfl_xor(tmax[mg][j], o));
#pragma unroll
    for (int mg = 0; mg < 2; ++mg)
#pragma unroll
      for (int j = 0; j < 4; ++j) {
        float mo = mrun[mg][j];
        float mn = fmaxf(mo, tmax[mg][j]);
        float sf = __expf(mo - mn);
        mrun[mg][j] = mn;
        lrun[mg][j] *= sf;
#pragma unroll
        for (int dn = 0; dn < 6; ++dn) oacc[mg][dn][j] *= sf;
      }
#pragma unroll
    for (int mg = 0; mg < 2; ++mg)
#pragma unroll
      for (int n = 0; n < 4; ++n)
#pragma unroll
        for (int j = 0; j < 4; ++j) {
          float p = __expf(sc[mg][n][j] - mrun[mg][j]);
          lrun[mg][j] += p;
          Pw[(mg * 16 + (l >> 4) * 4 + j) * 72 + n * 16 + (l & 15)] = (__bf16)p;
        }

#pragma unroll
    for (int ks = 0; ks < 2; ++ks) {
      bf16x8 pa0 = *(const bf16x8*)&Pw[((l & 15)) * 72 + ks * 32 + (l >> 4) * 8];
      bf16x8 pa1 = *(const bf16x8*)&Pw[(16 + (l & 15)) * 72 + ks * 32 + (l >> 4) * 8];
#pragma unroll
      for (int dn = 0; dn < 6; ++dn) {
        bf16x8 vb = *(const bf16x8*)&Vt[(dn * 16 + (l & 15)) * 88 + ks * 32 + (l >> 4) * 8];
        oacc[0][dn] = __builtin_amdgcn_mfma_f32_16x16x32_bf16(pa0, vb, oacc[0][dn], 0, 0, 0);
        oacc[1][dn] = __builtin_amdgcn_mfma_f32_16x16x32_bf16(pa1, vb, oacc[1][dn], 0, 0, 0);
      }
    }
  }

#pragma unroll
  for (int o = 1; o < 16; o <<= 1)
#pragma unroll
    for (int mg = 0; mg < 2; ++mg)
#pragma unroll
      for (int j = 0; j < 4; ++j)
        lrun[mg][j] += __shfl_xor(lrun[mg][j], o);

  const int b = bh >> 4, h = bh & 15;
#pragma unroll
  for (int mg = 0; mg < 2; ++mg) {
    float inv[4];
#pragma unroll
    for (int j = 0; j < 4; ++j) inv[j] = 1.f / lrun[mg][j];
    const int sqb = q0 + w * 32 + mg * 16 + (l >> 4) * 4;
#pragma unroll
    for (int dn = 0; dn < 6; ++dn) {
      const int d = dn * 16 + (l & 15);
      if (d >= 88) continue;
#pragma unroll
      for (int j = 0; j < 4; ++j) {
        const int sq = sqb + j;
        if (sq < 577)
          ctx[((size_t)(b * 577 + sq)) * 1408 + h * 88 + d] = (__bf16)(oacc[mg][dn][j] * inv[j]);
      }
    }
  }
}

extern "C" void kernel_launch(void* const* d_in, const int* in_sizes, int n_in,
                              void* d_out, int out_size, void* d_ws, size_t ws_size,
                              hipStream_t stream) {
  const float* hs    = (const float*)d_in[0];
  const float* freqs = (const float*)d_in[1];
  const float* wqkv  = (const float*)d_in[2];
  const float* bqkv  = (const float*)d_in[3];
  const float* wo    = (const float*)d_in[4];
  const float* bo    = (const float*)d_in[5];
  float* out = (float*)d_out;

  char* ws = (char*)d_ws;
  size_t off = 0;
  auto alloc = [&](size_t bytes) {
    void* p = ws + off;
    off += (bytes + 255) & ~(size_t)255;
    return p;
  };
  __bf16* x_bf    = (__bf16*)alloc((size_t)MROWS * K_ * 2);
  __bf16* ctx_bf  = x_bf;  // aliased: x dead after GEMM1
  __bf16* wqkv_bf = (__bf16*)alloc((size_t)N1 * K_ * 2);
  __bf16* wo_bf   = (__bf16*)alloc((size_t)D_ * K_ * 2);
  __bf16* q_bf    = (__bf16*)alloc((size_t)MROWS * D_ * 2);
  __bf16* k_bf    = (__bf16*)alloc((size_t)MROWS * D_ * 2);
  __bf16* v_bf    = (__bf16*)alloc((size_t)MROWS * D_ * 2);
  __bf16* vt_g    = (__bf16*)d_out;  // V^T scratch in d_out; GEMM2 overwrites later

  cast_bf16_kernel<<<(MROWS * K_ / 4 + 255) / 256, 256, 0, stream>>>(hs, x_bf, MROWS * K_ / 4);
  cast_bf16_kernel<<<(N1 * K_ / 4 + 255) / 256, 256, 0, stream>>>(wqkv, wqkv_bf, N1 * K_ / 4);
  cast_bf16_kernel<<<(D_ * K_ / 4 + 255) / 256, 256, 0, stream>>>(wo, wo_bf, D_ * K_ / 4);

  gemm_qkv_rope<<<33 * 73, 256, 0, stream>>>(x_bf, wqkv_bf, bqkv, freqs, q_bf, k_bf, v_bf);

  transpose_v<<<dim3(256, 10), 256, 0, stream>>>(v_bf, vt_g);

  attn_kernel<<<dim3(256, 5), 256, 0, stream>>>(q_bf, k_bf, vt_g, ctx_bf);

  gemm_out_bias<<<11 * 73, 256, 0, stream>>>(ctx_bf, wo_bf, bo, out);
}

// Round 11
// 388.566 us; speedup vs baseline: 4.8113x; 1.0115x over previous
//
#include <hip/hip_runtime.h>

typedef __attribute__((ext_vector_type(8))) __bf16 bf16x8;
typedef __attribute__((ext_vector_type(4))) float f32x4;
typedef __attribute__((ext_vector_type(4))) unsigned int uint4v;

#define B_ 16
#define S_ 577
#define D_ 1408
#define H_ 16
#define HD_ 88
#define MROWS (B_*S_)   // 9232
#define N1 (3*D_)       // 4224
#define K_ D_           // 1408
#define KSTEPS 44       // 1408/32
#define VT_LD 592
// q pre-scale: (1/sqrt(88)) * log2(e)  -> QK^T emits log2-space scores
#define QSCALE 0.15379180809f

static __device__ __forceinline__ void async16(void* lds, const void* g) {
  __builtin_amdgcn_global_load_lds((const __attribute__((address_space(1))) void*)g,
                                   (__attribute__((address_space(3))) void*)lds, 16, 0, 0);
}

// bijective XCD-aware remap (m204): contiguous wgid chunk per XCD
static __device__ __forceinline__ int xcd_swizzle(int orig, int nwg) {
  int xcd = orig & 7, lid = orig >> 3;
  int q = nwg >> 3, r = nwg & 7;
  return (xcd < r ? xcd * (q + 1) : r * (q + 1) + (xcd - r) * q) + lid;
}

// ---------------- merged cast fp32 -> bf16 (3 arrays, one launch) ----------------
__global__ void cast3_bf16_kernel(const float* __restrict__ s0, __bf16* __restrict__ d0, int n0,
                                  const float* __restrict__ s1, __bf16* __restrict__ d1, int n1,
                                  const float* __restrict__ s2, __bf16* __restrict__ d2, int n2) {
  int i = blockIdx.x * blockDim.x + threadIdx.x;
  const float* s; __bf16* d; int k;
  if (i < n0) { s = s0; d = d0; k = i; }
  else if (i < n0 + n1) { s = s1; d = d1; k = i - n0; }
  else if (i < n0 + n1 + n2) { s = s2; d = d2; k = i - n0 - n1; }
  else return;
  const float4 v = ((const float4*)s)[k];
  __bf16* p = d + (size_t)k * 4;
  p[0] = (__bf16)v.x; p[1] = (__bf16)v.y; p[2] = (__bf16)v.z; p[3] = (__bf16)v.w;
}

// ---------------- GEMM1: qkv = x @ Wqkv^T + b, fused RoPE+split+permute ----------------
// 128x128 tile, BK=32, 2-phase dbuf, L2-band tile order. q pre-scaled by QSCALE.
__launch_bounds__(256, 2)
__global__ void gemm_qkv_rope(const __bf16* __restrict__ A, const __bf16* __restrict__ Bm,
                              const float* __restrict__ bias, const float* __restrict__ freqs,
                              __bf16* __restrict__ Qb, __bf16* __restrict__ Kb,
                              __bf16* __restrict__ Vb) {
  __shared__ __bf16 As[2][128 * 32];
  __shared__ __bf16 Bs[2][128 * 32];
  const int tid = threadIdx.x;
  const int w = tid >> 6, l = tid & 63;
  const int wgid = xcd_swizzle(blockIdx.x, 33 * 73);
  int mt, nt;
  if (wgid < 2376) { int bnd = wgid / 132, r = wgid % 132; nt = r >> 2; mt = bnd * 4 + (r & 3); }
  else             { nt = wgid - 2376; mt = 72; }
  const int m0 = mt * 128, n0 = nt * 128;
  const int wr = w & 1, wc = w >> 1;
  const int M = MROWS, K = K_;

  f32x4 acc[4][4];
#pragma unroll
  for (int m = 0; m < 4; ++m)
#pragma unroll
    for (int n = 0; n < 4; ++n) acc[m][n] = (f32x4){0.f, 0.f, 0.f, 0.f};

  int arow0 = m0 + w * 32 + (l >> 2);      if (arow0 >= M) arow0 = M - 1;
  int arow1 = m0 + w * 32 + 16 + (l >> 2); if (arow1 >= M) arow1 = M - 1;
  const __bf16* ag0 = A + (size_t)arow0 * K + (l & 3) * 8;
  const __bf16* ag1 = A + (size_t)arow1 * K + (l & 3) * 8;
  const __bf16* bg0 = Bm + (size_t)(n0 + w * 32 + (l >> 2)) * K + (l & 3) * 8;
  const __bf16* bg1 = Bm + (size_t)(n0 + w * 32 + 16 + (l >> 2)) * K + (l & 3) * 8;

  auto stage = [&](int buf, int k0) {
    async16(&As[buf][(w * 32) * 32],      ag0 + k0);
    async16(&As[buf][(w * 32 + 16) * 32], ag1 + k0);
    async16(&Bs[buf][(w * 32) * 32],      bg0 + k0);
    async16(&Bs[buf][(w * 32 + 16) * 32], bg1 + k0);
  };

  stage(0, 0);
  __syncthreads();
  for (int t = 0; t < KSTEPS; ++t) {
    const int cur = t & 1;
    if (t < KSTEPS - 1) stage(cur ^ 1, (t + 1) * 32);
    bf16x8 a[4], b[4];
#pragma unroll
    for (int m = 0; m < 4; ++m)
      a[m] = *(const bf16x8*)&As[cur][(wr * 64 + m * 16 + (l & 15)) * 32 + (l >> 4) * 8];
#pragma unroll
    for (int n = 0; n < 4; ++n)
      b[n] = *(const bf16x8*)&Bs[cur][(wc * 64 + n * 16 + (l & 15)) * 32 + (l >> 4) * 8];
#pragma unroll
    for (int m = 0; m < 4; ++m)
#pragma unroll
      for (int n = 0; n < 4; ++n)
        acc[m][n] = __builtin_amdgcn_mfma_f32_16x16x32_bf16(a[m], b[n], acc[m][n], 0, 0, 0);
    __syncthreads();
  }

  // ---- epilogue: bias + RoPE + q-prescale + head-major store ----
  const int sect = n0 / 1408;  // 0=q 1=k 2=v, uniform per block
  __bf16* dst = (sect == 0) ? Qb : (sect == 1 ? Kb : Vb);
  const float qs = (sect == 0) ? QSCALE : 1.f;
  int hN[4], dN[4], i2N[4];
  float bvN[4], sgnN[4];
#pragma unroll
  for (int n = 0; n < 4; ++n) {
    const int col = n0 + wc * 64 + n * 16 + (l & 15);
    const int cin = col - sect * 1408;
    hN[n] = cin / 88; dN[n] = cin - hN[n] * 88;
    bvN[n] = bias[col];
    i2N[n] = dN[n] & ~1;
    sgnN[n] = (dN[n] & 1) ? 1.f : -1.f;
  }
#pragma unroll
  for (int m = 0; m < 4; ++m) {
    const int rbase = m0 + wr * 64 + m * 16 + (l >> 4) * 4;
#pragma unroll
    for (int j = 0; j < 4; ++j) {
      const int r = rbase + j;
      const int s = r % 577;
      const int b = r / 577;
      const bool ok = r < MROWS;
      const float* frow = freqs + s * 88;
      __bf16* drow = dst + ((size_t)b * 16 * 577 + s) * 88;
#pragma unroll
      for (int n = 0; n < 4; ++n) {
        float val = acc[m][n][j] + bvN[n];
        float outv = val;
        if (sect < 2) {
          const float2 cs = *(const float2*)&frow[i2N[n]];
          const float p = __shfl_xor(val, 1);   // all lanes execute
          outv = (val * cs.x + sgnN[n] * p * cs.y) * qs;
        }
        if (ok) drow[(size_t)hN[n] * 50776 + dN[n]] = (__bf16)outv;  // 50776 = 577*88
      }
    }
  }
}

// ---------------- GEMM2: out = ctx @ Wo^T + bo (fp32 out), same 2-phase loop ----------------
__launch_bounds__(256, 2)
__global__ void gemm_out_bias(const __bf16* __restrict__ A, const __bf16* __restrict__ Bm,
                              const float* __restrict__ bias, float* __restrict__ C) {
  __shared__ __bf16 As[2][128 * 32];
  __shared__ __bf16 Bs[2][128 * 32];
  const int tid = threadIdx.x;
  const int w = tid >> 6, l = tid & 63;
  const int wgid = xcd_swizzle(blockIdx.x, 11 * 73);
  int mt, nt;
  if (wgid < 792) { int bnd = wgid / 44, r = wgid % 44; nt = r >> 2; mt = bnd * 4 + (r & 3); }
  else            { nt = wgid - 792; mt = 72; }
  const int m0 = mt * 128, n0 = nt * 128;
  const int wr = w & 1, wc = w >> 1;
  const int M = MROWS, N = D_, K = K_;

  f32x4 acc[4][4];
#pragma unroll
  for (int m = 0; m < 4; ++m)
#pragma unroll
    for (int n = 0; n < 4; ++n) acc[m][n] = (f32x4){0.f, 0.f, 0.f, 0.f};

  int arow0 = m0 + w * 32 + (l >> 2);      if (arow0 >= M) arow0 = M - 1;
  int arow1 = m0 + w * 32 + 16 + (l >> 2); if (arow1 >= M) arow1 = M - 1;
  const __bf16* ag0 = A + (size_t)arow0 * K + (l & 3) * 8;
  const __bf16* ag1 = A + (size_t)arow1 * K + (l & 3) * 8;
  const __bf16* bg0 = Bm + (size_t)(n0 + w * 32 + (l >> 2)) * K + (l & 3) * 8;
  const __bf16* bg1 = Bm + (size_t)(n0 + w * 32 + 16 + (l >> 2)) * K + (l & 3) * 8;

  auto stage = [&](int buf, int k0) {
    async16(&As[buf][(w * 32) * 32],      ag0 + k0);
    async16(&As[buf][(w * 32 + 16) * 32], ag1 + k0);
    async16(&Bs[buf][(w * 32) * 32],      bg0 + k0);
    async16(&Bs[buf][(w * 32 + 16) * 32], bg1 + k0);
  };

  stage(0, 0);
  __syncthreads();
  for (int t = 0; t < KSTEPS; ++t) {
    const int cur = t & 1;
    if (t < KSTEPS - 1) stage(cur ^ 1, (t + 1) * 32);
    bf16x8 a[4], b[4];
#pragma unroll
    for (int m = 0; m < 4; ++m)
      a[m] = *(const bf16x8*)&As[cur][(wr * 64 + m * 16 + (l & 15)) * 32 + (l >> 4) * 8];
#pragma unroll
    for (int n = 0; n < 4; ++n)
      b[n] = *(const bf16x8*)&Bs[cur][(wc * 64 + n * 16 + (l & 15)) * 32 + (l >> 4) * 8];
#pragma unroll
    for (int m = 0; m < 4; ++m)
#pragma unroll
      for (int n = 0; n < 4; ++n)
        acc[m][n] = __builtin_amdgcn_mfma_f32_16x16x32_bf16(a[m], b[n], acc[m][n], 0, 0, 0);
    __syncthreads();
  }

#pragma unroll
  for (int n = 0; n < 4; ++n) {
    int col = n0 + wc * 64 + n * 16 + (l & 15);
    float bv = bias[col];
#pragma unroll
    for (int m = 0; m < 4; ++m) {
      int rbase = m0 + wr * 64 + m * 16 + (l >> 4) * 4;
#pragma unroll
      for (int j = 0; j < 4; ++j) {
        int r = rbase + j;
        if (r < MROWS) C[(size_t)r * N + col] = acc[m][n][j] + bv;
      }
    }
  }
}

// ---------------- V transpose: v_bf [bh][577][88] -> Vt_g [bh][88][592] ----------------
__global__ void transpose_v(const __bf16* __restrict__ V, __bf16* __restrict__ Vt_g) {
  __shared__ __bf16 Ls[64 * 104];
  const int bh = blockIdx.x, t = blockIdx.y, s0 = t * 64;
  const int tid = threadIdx.x;
  const __bf16* vp = V + (size_t)bh * 577 * 88;
  for (int i = tid; i < 64 * 11; i += 256) {
    int r = i / 11, off = i % 11;
    int gs = s0 + r; if (gs > 576) gs = 576;
    *(uint4v*)&Ls[r * 104 + off * 8] = *(const uint4v*)(vp + (size_t)gs * 88 + off * 8);
  }
  __syncthreads();
  for (int i = tid; i < 88 * 8; i += 256) {
    int d = i / 8, so = (i % 8) * 8;
    int sc_ = s0 + so;
    if (sc_ < VT_LD) {
      __bf16 tmp[8];
#pragma unroll
      for (int j = 0; j < 8; ++j) tmp[j] = Ls[(so + j) * 104 + d];
      *(uint4v*)&Vt_g[((size_t)bh * 88 + d) * VT_LD + sc_] = *(uint4v*)tmp;
    }
  }
}

// ---------------- flash attention: block = (bh, 128 q-rows), 4 waves x 32 rows ----------------
// Scores arrive in log2-space (q pre-scaled by QSCALE); softmax uses exp2f;
// defer-max (THR=8): skip O/l rescale unless a row's max grew by >8.
__launch_bounds__(256, 3)
__global__ void attn_kernel(const __bf16* __restrict__ Q, const __bf16* __restrict__ K,
                            const __bf16* __restrict__ Vt_gp, __bf16* __restrict__ ctx) {
  __shared__ __bf16 lds[26368];
  const int tid = threadIdx.x;
  const int w = tid >> 6, l = tid & 63;
  const int bh = blockIdx.x;
  const int q0 = blockIdx.y * 128;
  const __bf16* qp = Q + (size_t)bh * 577 * 88;
  const __bf16* kp = K + (size_t)bh * 577 * 88;
  const __bf16* vtp = Vt_gp + (size_t)bh * 88 * VT_LD;
  __bf16* Qs = lds;             // [128][96]
  __bf16* Ks = lds + 12288;     // [64][88]
  __bf16* Vt = lds + 17920;     // [96][88]
  __bf16* Pw = lds + w * 2304;  // per-wave P [32][72]

  for (int i = tid; i < 128 * 11; i += 256) {
    int r = i / 11, off = i % 11;
    int gr = q0 + r; if (gr > 576) gr = 576;
    *(uint4v*)&Qs[r * 96 + off * 8] = *(const uint4v*)(qp + (size_t)gr * 88 + off * 8);
  }
  if (tid < 128) { uint4v z = 0; *(uint4v*)&Qs[tid * 96 + 88] = z; }
  __syncthreads();

  bf16x8 qf[2][3];
#pragma unroll
  for (int mg = 0; mg < 2; ++mg)
#pragma unroll
    for (int kk = 0; kk < 3; ++kk)
      qf[mg][kk] = *(const bf16x8*)&Qs[(w * 32 + mg * 16 + (l & 15)) * 96 + kk * 32 + (l >> 4) * 8];

  int preA[7], preB[7];
#pragma unroll
  for (int kch = 0; kch < 7; ++kch) {
    int c = w + 4 * kch;
    int a = 0, b2 = 0;
    if (c < 11) a = c * 512 + l * 8;
    else if (c < 27) { int e = (c - 11) * 512 + l * 8; a = (e / 88) * VT_LD; b2 = e % 88; }
    preA[kch] = a; preB[kch] = b2;
  }

  f32x4 oacc[2][6];
#pragma unroll
  for (int mg = 0; mg < 2; ++mg)
#pragma unroll
    for (int dn = 0; dn < 6; ++dn) oacc[mg][dn] = (f32x4){0.f, 0.f, 0.f, 0.f};
  f32x4 mrun[2], lrun[2];
  mrun[0] = -1e30f; mrun[1] = -1e30f;
  lrun[0] = 0.f; lrun[1] = 0.f;

  for (int t = 0; t < 10; ++t) {
    const int s0 = t * 64;
    if (t) __syncthreads();
#pragma unroll
    for (int kch = 0; kch < 7; ++kch) {
      int c = w + 4 * kch;
      if (c < 11) {
        async16(Ks + c * 512, kp + (size_t)s0 * 88 + preA[kch]);
      } else if (c < 27) {
        int g = s0 + preB[kch]; if (g > 584) g = 584;
        async16(Vt + (c - 11) * 512, vtp + preA[kch] + g);
      }
    }
    __syncthreads();

    f32x4 sc[2][4];
#pragma unroll
    for (int mg = 0; mg < 2; ++mg)
#pragma unroll
      for (int n = 0; n < 4; ++n) sc[mg][n] = (f32x4){0.f, 0.f, 0.f, 0.f};
#pragma unroll
    for (int n = 0; n < 4; ++n) {
#pragma unroll
      for (int kk = 0; kk < 3; ++kk) {
        bf16x8 kf = *(const bf16x8*)&Ks[(n * 16 + (l & 15)) * 88 + kk * 32 + (l >> 4) * 8];
        sc[0][n] = __builtin_amdgcn_mfma_f32_16x16x32_bf16(qf[0][kk], kf, sc[0][n], 0, 0, 0);
        sc[1][n] = __builtin_amdgcn_mfma_f32_16x16x32_bf16(qf[1][kk], kf, sc[1][n], 0, 0, 0);
      }
    }

    // mask invalid cols (scores already log2-scaled)
    f32x4 tmax[2];
    tmax[0] = -1e30f; tmax[1] = -1e30f;
#pragma unroll
    for (int n = 0; n < 4; ++n) {
      const int kc = s0 + n * 16 + (l & 15);
      const bool valid = kc < 577;
#pragma unroll
      for (int mg = 0; mg < 2; ++mg)
#pragma unroll
        for (int j = 0; j < 4; ++j) {
          float v = valid ? sc[mg][n][j] : -1e30f;
          sc[mg][n][j] = v;
          tmax[mg][j] = fmaxf(tmax[mg][j], v);
        }
    }
#pragma unroll
    for (int o = 1; o < 16; o <<= 1)
#pragma unroll
      for (int mg = 0; mg < 2; ++mg)
#pragma unroll
        for (int j = 0; j < 4; ++j)
          tmax[mg][j] = fmaxf(tmax[mg][j], __shfl_xor(tmax[mg][j], o));

    // defer-max: rescale only when some row's max grew by > 8 (log2 space)
    bool need = false;
#pragma unroll
    for (int mg = 0; mg < 2; ++mg)
#pragma unroll
      for (int j = 0; j < 4; ++j)
        need = need || (tmax[mg][j] > mrun[mg][j] + 8.f);
    if (__any(need)) {
#pragma unroll
      for (int mg = 0; mg < 2; ++mg)
#pragma unroll
        for (int j = 0; j < 4; ++j) {
          float mo = mrun[mg][j];
          float mn = fmaxf(mo, tmax[mg][j]);
          float sf = exp2f(mo - mn);
          mrun[mg][j] = mn;
          lrun[mg][j] *= sf;
#pragma unroll
          for (int dn = 0; dn < 6; ++dn) oacc[mg][dn][j] *= sf;
        }
    }
#pragma unroll
    for (int mg = 0; mg < 2; ++mg)
#pragma unroll
      for (int n = 0; n < 4; ++n)
#pragma unroll
        for (int j = 0; j < 4; ++j) {
          float p = exp2f(sc[mg][n][j] - mrun[mg][j]);   // bounded by 2^8
          lrun[mg][j] += p;
          Pw[(mg * 16 + (l >> 4) * 4 + j) * 72 + n * 16 + (l & 15)] = (__bf16)p;
        }

#pragma unroll
    for (int ks = 0; ks < 2; ++ks) {
      bf16x8 pa0 = *(const bf16x8*)&Pw[((l & 15)) * 72 + ks * 32 + (l >> 4) * 8];
      bf16x8 pa1 = *(const bf16x8*)&Pw[(16 + (l & 15)) * 72 + ks * 32 + (l >> 4) * 8];
#pragma unroll
      for (int dn = 0; dn < 6; ++dn) {
        bf16x8 vb = *(const bf16x8*)&Vt[(dn * 16 + (l & 15)) * 88 + ks * 32 + (l >> 4) * 8];
        oacc[0][dn] = __builtin_amdgcn_mfma_f32_16x16x32_bf16(pa0, vb, oacc[0][dn], 0, 0, 0);
        oacc[1][dn] = __builtin_amdgcn_mfma_f32_16x16x32_bf16(pa1, vb, oacc[1][dn], 0, 0, 0);
      }
    }
  }

#pragma unroll
  for (int o = 1; o < 16; o <<= 1)
#pragma unroll
    for (int mg = 0; mg < 2; ++mg)
#pragma unroll
      for (int j = 0; j < 4; ++j)
        lrun[mg][j] += __shfl_xor(lrun[mg][j], o);

  const int b = bh >> 4, h = bh & 15;
#pragma unroll
  for (int mg = 0; mg < 2; ++mg) {
    float inv[4];
#pragma unroll
    for (int j = 0; j < 4; ++j) inv[j] = 1.f / lrun[mg][j];
    const int sqb = q0 + w * 32 + mg * 16 + (l >> 4) * 4;
#pragma unroll
    for (int dn = 0; dn < 6; ++dn) {
      const int d = dn * 16 + (l & 15);
      if (d >= 88) continue;
#pragma unroll
      for (int j = 0; j < 4; ++j) {
        const int sq = sqb + j;
        if (sq < 577)
          ctx[((size_t)(b * 577 + sq)) * 1408 + h * 88 + d] = (__bf16)(oacc[mg][dn][j] * inv[j]);
      }
    }
  }
}

extern "C" void kernel_launch(void* const* d_in, const int* in_sizes, int n_in,
                              void* d_out, int out_size, void* d_ws, size_t ws_size,
                              hipStream_t stream) {
  const float* hs    = (const float*)d_in[0];
  const float* freqs = (const float*)d_in[1];
  const float* wqkv  = (const float*)d_in[2];
  const float* bqkv  = (const float*)d_in[3];
  const float* wo    = (const float*)d_in[4];
  const float* bo    = (const float*)d_in[5];
  float* out = (float*)d_out;

  char* ws = (char*)d_ws;
  size_t off = 0;
  auto alloc = [&](size_t bytes) {
    void* p = ws + off;
    off += (bytes + 255) & ~(size_t)255;
    return p;
  };
  __bf16* x_bf    = (__bf16*)alloc((size_t)MROWS * K_ * 2);
  __bf16* ctx_bf  = x_bf;  // aliased: x dead after GEMM1
  __bf16* wqkv_bf = (__bf16*)alloc((size_t)N1 * K_ * 2);
  __bf16* wo_bf   = (__bf16*)alloc((size_t)D_ * K_ * 2);
  __bf16* q_bf    = (__bf16*)alloc((size_t)MROWS * D_ * 2);
  __bf16* k_bf    = (__bf16*)alloc((size_t)MROWS * D_ * 2);
  __bf16* v_bf    = (__bf16*)alloc((size_t)MROWS * D_ * 2);
  __bf16* vt_g    = (__bf16*)d_out;  // V^T scratch in d_out; GEMM2 overwrites later

  const int n0 = MROWS * K_ / 4, n1 = N1 * K_ / 4, n2 = D_ * K_ / 4;
  cast3_bf16_kernel<<<(n0 + n1 + n2 + 255) / 256, 256, 0, stream>>>(
      hs, x_bf, n0, wqkv, wqkv_bf, n1, wo, wo_bf, n2);

  gemm_qkv_rope<<<33 * 73, 256, 0, stream>>>(x_bf, wqkv_bf, bqkv, freqs, q_bf, k_bf, v_bf);

  transpose_v<<<dim3(256, 10), 256, 0, stream>>>(v_bf, vt_g);

  attn_kernel<<<dim3(256, 5), 256, 0, stream>>>(q_bf, k_bf, vt_g, ctx_bf);

  gemm_out_bias<<<11 * 73, 256, 0, stream>>>(ctx_bf, wo_bf, bo, out);
}